// Round 1
// baseline (309.917 us; speedup 1.0000x reference)
//
#include <hip/hip_runtime.h>
#include <hip/hip_bf16.h>

#define PI_D 3.14159265358979323846
#define L_TOTAL 2097152
#define NFRAMES 4105      // 1 + L/511
#define MROWS   8210      // 2*NFRAMES (x/y interleaved)
#define MPAD    8320      // 65 * 128
#define KDIM    2048      // 2046 padded
#define NDIM    2048      // 1024 bins * (Re,Im)

typedef __attribute__((ext_vector_type(8))) short short8;
typedef __attribute__((ext_vector_type(4))) float floatx4;

typedef __attribute__((address_space(1))) void gvoid_as1;
typedef __attribute__((address_space(3))) void lvoid_as3;

__device__ __forceinline__ void gld_lds16(const void* g, void* l) {
    __builtin_amdgcn_global_load_lds((gvoid_as1*)g, (lvoid_as3*)l, 16, 0, 0);
}

__device__ __forceinline__ float wave_reduce(float v) {
    v += __shfl_down(v, 32, 64);
    v += __shfl_down(v, 16, 64);
    v += __shfl_down(v, 8, 64);
    v += __shfl_down(v, 4, 64);
    v += __shfl_down(v, 2, 64);
    v += __shfl_down(v, 1, 64);
    return v;
}

// ---------------- zero workspace accumulators ----------------
__global__ void zero_kernel(float* __restrict__ p, int n) {
    int i = blockIdx.x * 256 + threadIdx.x;
    if (i < n) p[i] = 0.f;
}

// ---------------- Burg LPC: one block per 1024-sample audio block ----------------
__global__ void burg_kernel(const float* __restrict__ y, float* __restrict__ ar_out) {
    __shared__ float fbuf[2][1023];
    __shared__ float bbuf[2][1023];
    __shared__ float red[4];
    __shared__ float sh_k, sh_den;
    __shared__ float ar_s[13];
    const int tid = threadIdx.x;
    const float* yb = y + (size_t)blockIdx.x * 1024;

    for (int n = tid; n < 1023; n += 256) {
        fbuf[0][n] = yb[n + 1];
        bbuf[0][n] = yb[n];
    }
    if (tid < 13) ar_s[tid] = (tid == 0) ? 1.f : 0.f;
    __syncthreads();

    // den = sum f^2 + sum b^2
    float lo = 0.f;
    for (int n = tid; n < 1023; n += 256)
        lo += fbuf[0][n] * fbuf[0][n] + bbuf[0][n] * bbuf[0][n];
    lo = wave_reduce(lo);
    if ((tid & 63) == 0) red[tid >> 6] = lo;
    __syncthreads();
    if (tid == 0) sh_den = red[0] + red[1] + red[2] + red[3];
    __syncthreads();

    int cur = 0;
    for (int i = 0; i < 12; i++) {
        const int len = 1023 - i;
        float acc = 0.f;
        for (int n = tid; n < len; n += 256) acc += fbuf[cur][n] * bbuf[cur][n];
        acc = wave_reduce(acc);
        if ((tid & 63) == 0) red[tid >> 6] = acc;
        __syncthreads();
        if (tid == 0) {
            float num = red[0] + red[1] + red[2] + red[3];
            sh_k = -2.f * num / sh_den;
        }
        __syncthreads();
        const float k = sh_k;
        const int nxt = cur ^ 1;
        for (int n = tid; n < len - 1; n += 256) {
            fbuf[nxt][n] = fbuf[cur][n + 1] + k * bbuf[cur][n + 1]; // f_new[1:]
            bbuf[nxt][n] = bbuf[cur][n] + k * fbuf[cur][n];         // b_new[:-1]
        }
        if (tid == 0) {
            float f0 = fbuf[cur][0] + k * bbuf[cur][0];               // f_new[0]
            float bl = bbuf[cur][len - 1] + k * fbuf[cur][len - 1];   // b_new[-1]
            sh_den = (1.f - k * k) * sh_den - bl * bl - f0 * f0;
            float tmp[13];
            for (int js = 1; js <= i + 1; js++) tmp[js] = ar_s[js] + k * ar_s[i - js + 1];
            for (int js = 1; js <= i + 1; js++) ar_s[js] = tmp[js];
        }
        __syncthreads();
        cur = nxt;
    }
    if (tid < 12) ar_out[(size_t)blockIdx.x * 12 + tid] = ar_s[tid];
}

// ---------------- invW[f] = sum_{b,kk} |den(b,kk,f)| / |num(b,kk,f)| ----------------
// grid (4, 32): blockIdx.x covers f in chunks of 256, blockIdx.y covers b in chunks of 64
__global__ void invw_kernel(const float* __restrict__ ar, float* __restrict__ invW) {
    __shared__ float sar[64][12];
    const int tid = threadIdx.x;
    const int f = blockIdx.x * 256 + tid;
    const int b0 = blockIdx.y * 64;
    for (int idx = tid; idx < 64 * 12; idx += 256)
        ((float*)sar)[idx] = ar[(size_t)b0 * 12 + idx];
    __syncthreads();

    const float omega = (float)(PI_D / 1024.0) * (float)f;
    float sw, cw;
    __sincosf(omega, &sw, &cw);

    float acc = 0.f;
    for (int bb = 0; bb < 64; bb++) {
        float a0 = sar[bb][0];
        float nr = a0, ni = 0.f, dr = a0, di = 0.f; // num: G=0.6 series, den: G=0.92 series
        float er = 1.f, ei = 0.f;
        float g1p = 1.f, g2p = 1.f;
        for (int j = 1; j < 12; j++) {
            // E *= e^{-i omega}
            float er2 = er * cw + ei * sw;
            float ei2 = ei * cw - er * sw;
            er = er2; ei = ei2;
            g1p *= 0.92f; g2p *= 0.6f;
            float aj = sar[bb][j];
            float a1 = aj * g1p, a2 = aj * g2p;
            nr += a2 * er; ni += a2 * ei;
            dr += a1 * er; di += a1 * ei;
            // kk = j-1: 1/W = |den|/|num|
            acc += sqrtf((dr * dr + di * di) / (nr * nr + ni * ni));
        }
    }
    atomicAdd(&invW[f], acc);
}

// ---------------- build frame matrix A (bf16), rows interleaved x/y ----------------
__global__ void frames_kernel(const float* __restrict__ x, const float* __restrict__ y,
                              __hip_bfloat16* __restrict__ A) {
    const int idx = blockIdx.x * 256 + threadIdx.x;
    const int r = idx >> 11;      // row (frame-pair interleaved)
    const int c = idx & 2047;     // k
    float v = 0.f;
    if (r < MROWS && c < 2046) {
        const int t = r >> 1;
        int p = t * 511 + c - 1023;          // reflect-padded index into signal
        if (p < 0) p = -p;
        else if (p >= L_TOTAL) p = 2 * L_TOTAL - 2 - p;
        v = (r & 1) ? y[p] : x[p];
    }
    A[idx] = __float2bfloat16(v);
}

// ---------------- build DFT basis B^T (bf16): row = 2f (cos) / 2f+1 (-sin), col = k ----------------
__global__ void basis_kernel(__hip_bfloat16* __restrict__ Bt) {
    const int idx = blockIdx.x * 256 + threadIdx.x;
    const int row = idx >> 11;    // output column index (interleaved Re/Im)
    const int k = idx & 2047;
    float v = 0.f;
    if (k < 2046) {
        const int f = row >> 1;
        const int m = (k * f) % 2046;        // exact angle reduction mod 2pi
        const float ang = (float)m * (float)(PI_D / 1023.0);
        float s, c;
        __sincosf(ang, &s, &c);
        v = (row & 1) ? -s : c;
    }
    Bt[idx] = __float2bfloat16(v);
}

// ---------------- GEMM (m97 structure) + fused |X|-|Y| mse epilogue ----------------
// C[M,N] = A[M,K] * Bt[N,K]^T ; 128x128 tile, 4 waves of 4x4 16x16x32 MFMA
__global__ __launch_bounds__(256) void gemm_mse_kernel(
    const __hip_bfloat16* __restrict__ A, const __hip_bfloat16* __restrict__ Bt,
    float* __restrict__ mse_sum) {
    __shared__ __align__(16) __hip_bfloat16 Al[128 * 32];
    __shared__ __align__(16) __hip_bfloat16 Bl[128 * 32];
    __shared__ float msePart[64];

    const int tid = threadIdx.x;
    const int lane = tid & 63;
    const int w = tid >> 6;
    const int wm = w >> 1, wn = w & 1;
    const int q = lane >> 4, l15 = lane & 15;
    const int tileM = blockIdx.x * 128;
    const int tileN = blockIdx.y * 128;

    floatx4 acc[4][4];
    for (int i = 0; i < 4; i++)
        for (int j = 0; j < 4; j++) acc[i][j] = (floatx4){0.f, 0.f, 0.f, 0.f};

    // staging indices: fi in [0,512), 16B per slot; LDS layout row-major [128][32] bf16
    const int fi0 = tid, fi1 = 256 + tid;
    const int row0 = fi0 >> 2, row1 = fi1 >> 2;
    const int c0 = (fi0 & 3) << 3, c1 = (fi1 & 3) << 3;
    const __hip_bfloat16* Ab0 = A + (size_t)(tileM + row0) * KDIM + c0;
    const __hip_bfloat16* Ab1 = A + (size_t)(tileM + row1) * KDIM + c1;
    const __hip_bfloat16* Bb0 = Bt + (size_t)(tileN + row0) * KDIM + c0;
    const __hip_bfloat16* Bb1 = Bt + (size_t)(tileN + row1) * KDIM + c1;
    char* AlB = (char*)Al;
    char* BlB = (char*)Bl;

    for (int kk = 0; kk < KDIM; kk += 32) {
        gld_lds16(Ab0 + kk, AlB + fi0 * 16);
        gld_lds16(Ab1 + kk, AlB + fi1 * 16);
        gld_lds16(Bb0 + kk, BlB + fi0 * 16);
        gld_lds16(Bb1 + kk, BlB + fi1 * 16);
        __syncthreads();

        short8 af[4], bf[4];
        for (int sm = 0; sm < 4; sm++)
            af[sm] = *(const short8*)(AlB + ((wm * 64 + sm * 16 + l15) * 32 + q * 8) * 2);
        for (int sn = 0; sn < 4; sn++)
            bf[sn] = *(const short8*)(BlB + ((wn * 64 + sn * 16 + l15) * 32 + q * 8) * 2);
        for (int sm = 0; sm < 4; sm++)
            for (int sn = 0; sn < 4; sn++)
                acc[sm][sn] = __builtin_amdgcn_mfma_f32_16x16x32_bf16(
                    af[sm], bf[sn], acc[sm][sn], 0, 0, 0);
        __syncthreads();
    }

    // epilogue: C/D layout col=lane&15 (N), row=quad*4+reg (M).
    // even row = X frame, odd row = Y frame; even col = Re, odd col = Im.
    if (tid < 64) msePart[tid] = 0.f;
    __syncthreads();
    const bool evenLane = (l15 & 1) == 0;
    for (int sm = 0; sm < 4; sm++) {
        for (int sn = 0; sn < 4; sn++) {
            for (int rp = 0; rp < 2; rp++) {
                float vE = acc[sm][sn][2 * rp];       // X (even row), this col
                float vO = acc[sm][sn][2 * rp + 1];   // Y (odd row), this col
                float pE = __shfl_xor(vE, 1, 64);     // partner col (Re<->Im)
                float pO = __shfl_xor(vO, 1, 64);
                if (evenLane) {
                    float magX = sqrtf(vE * vE + pE * pE);
                    float magY = sqrtf(vO * vO + pO * pO);
                    float d = magX - magY;
                    int fl = (wn * 64 + sn * 16 + l15) >> 1;
                    atomicAdd(&msePart[fl], d * d);
                }
            }
        }
    }
    __syncthreads();
    if (tid < 64) atomicAdd(&mse_sum[(tileN >> 1) + tid], msePart[tid]);
}

// ---------------- final: out = sum_f mse_sum[f]*invW[f] / (4105*22528*1024) ----------------
__global__ void final_kernel(const float* __restrict__ mse_sum,
                             const float* __restrict__ invW,
                             float* __restrict__ out) {
    __shared__ float red[4];
    const int tid = threadIdx.x;
    float lo = 0.f;
    for (int f = tid; f < 1024; f += 256) lo += mse_sum[f] * invW[f];
    lo = wave_reduce(lo);
    if ((tid & 63) == 0) red[tid >> 6] = lo;
    __syncthreads();
    if (tid == 0) {
        float tot = red[0] + red[1] + red[2] + red[3];
        out[0] = tot * (float)(1.0 / (4105.0 * 22528.0 * 1024.0));
    }
}

extern "C" void kernel_launch(void* const* d_in, const int* in_sizes, int n_in,
                              void* d_out, int out_size, void* d_ws, size_t ws_size,
                              hipStream_t stream) {
    const float* x = (const float*)d_in[0];
    const float* y = (const float*)d_in[1];
    float* out = (float*)d_out;

    float* wsf = (float*)d_ws;
    float* mse_sum = wsf;             // 1024 floats
    float* invW = wsf + 1024;         // 1024 floats
    float* ar = wsf + 2048;           // 2048*12 floats (ends at byte 106496)
    __hip_bfloat16* A = (__hip_bfloat16*)((char*)d_ws + 131072);     // 8320*2048*2 = 34,078,720 B
    __hip_bfloat16* Bt = (__hip_bfloat16*)((char*)d_ws + 34209792);  // 2048*2048*2 = 8,388,608 B

    zero_kernel<<<8, 256, 0, stream>>>(wsf, 2048);
    burg_kernel<<<2048, 256, 0, stream>>>(y, ar);
    invw_kernel<<<dim3(4, 32), 256, 0, stream>>>(ar, invW);
    frames_kernel<<<(MPAD * KDIM) / 256, 256, 0, stream>>>(x, y, A);
    basis_kernel<<<(NDIM * KDIM) / 256, 256, 0, stream>>>(Bt);
    gemm_mse_kernel<<<dim3(MPAD / 128, NDIM / 128), 256, 0, stream>>>(A, Bt, mse_sum);
    final_kernel<<<1, 256, 0, stream>>>(mse_sum, invW, out);
}

// Round 2
// 297.402 us; speedup vs baseline: 1.0421x; 1.0421x over previous
//
#include <hip/hip_runtime.h>
#include <hip/hip_bf16.h>

#define PI_D 3.14159265358979323846
#define L_TOTAL 2097152
#define NFRAMES 4105      // 1 + L/511
#define MROWS   8210      // 2*NFRAMES (x/y interleaved)
#define MPAD    8320      // 65 * 128
#define KDIM    2048      // 2046 padded
#define NDIM    2048      // 1024 bins * (Re,Im)

typedef __attribute__((ext_vector_type(8))) short short8;
typedef __attribute__((ext_vector_type(4))) float floatx4;

typedef __attribute__((address_space(1))) void gvoid_as1;
typedef __attribute__((address_space(3))) void lvoid_as3;

__device__ __forceinline__ void gld_lds16(const void* g, void* l) {
    __builtin_amdgcn_global_load_lds((gvoid_as1*)g, (lvoid_as3*)l, 16, 0, 0);
}

__device__ __forceinline__ float xorall(float v) {
    v += __shfl_xor(v, 1, 64);
    v += __shfl_xor(v, 2, 64);
    v += __shfl_xor(v, 4, 64);
    v += __shfl_xor(v, 8, 64);
    v += __shfl_xor(v, 16, 64);
    v += __shfl_xor(v, 32, 64);
    return v;
}

__device__ __forceinline__ float wave_reduce(float v) {
    v += __shfl_down(v, 32, 64);
    v += __shfl_down(v, 16, 64);
    v += __shfl_down(v, 8, 64);
    v += __shfl_down(v, 4, 64);
    v += __shfl_down(v, 2, 64);
    v += __shfl_down(v, 1, 64);
    return v;
}

// ---------------- zero workspace accumulators ----------------
__global__ void zero_kernel(float* __restrict__ p, int n) {
    int i = blockIdx.x * 256 + threadIdx.x;
    if (i < n) p[i] = 0.f;
}

// ---------------- Burg LPC: one WAVE per 1024-sample audio block ----------------
// 1023-long f/b arrays live in registers: idx = r*64 + lane, r in [0,16).
// No LDS, no barriers: xor-butterfly reductions, shuffles for the shift-by-1.
__global__ __launch_bounds__(256) void burg_kernel(const float* __restrict__ y,
                                                   float* __restrict__ ar_out) {
    const int lane = threadIdx.x & 63;
    const int wid = threadIdx.x >> 6;
    const int blk = blockIdx.x * 4 + wid;
    const float* yb = y + (size_t)blk * 1024;

    float f[16], b[16];
#pragma unroll
    for (int r = 0; r < 16; r++) {
        const int idx = r * 64 + lane;
        const bool v = idx < 1023;
        b[r] = v ? yb[idx] : 0.f;
        f[r] = v ? yb[idx + 1] : 0.f;
    }

    float den = 0.f;
#pragma unroll
    for (int r = 0; r < 16; r++) den += f[r] * f[r] + b[r] * b[r];
    den = xorall(den);

    float ar_s[13];
    ar_s[0] = 1.f;
#pragma unroll
    for (int j = 1; j < 13; j++) ar_s[j] = 0.f;

#pragma unroll
    for (int i = 0; i < 12; i++) {
        const int len = 1023 - i;
        float num = 0.f;
#pragma unroll
        for (int r = 0; r < 16; r++) num += f[r] * b[r];
        num = xorall(num);
        const float k = -2.f * num / den;

        float fu[16], bu[16];
#pragma unroll
        for (int r = 0; r < 16; r++) {
            fu[r] = f[r] + k * b[r];
            bu[r] = b[r] + k * f[r];
        }
        const float f0 = __shfl(fu[0], 0, 64);
        const int rr = (len - 1) >> 6;        // == 15 for all i
        const int ll = (len - 1) & 63;        // 62 - i
        const float blast = __shfl(bu[rr], ll, 64);

        // f = fu shifted left by one position (idx -> idx+1); tail stays zero
#pragma unroll
        for (int r = 0; r < 16; r++) {
            float t = __shfl_down(fu[r], 1, 64);
            float w = (r < 15) ? __shfl(fu[r + 1], 0, 64) : 0.f;
            f[r] = (lane == 63) ? w : t;
        }
        // b = bu with position len-1 dropped (zeroed)
#pragma unroll
        for (int r = 0; r < 16; r++) b[r] = bu[r];
        if (lane == ll) b[rr] = 0.f;

        den = (1.f - k * k) * den - blast * blast - f0 * f0;

        float tmp[13];
#pragma unroll
        for (int js = 1; js <= i + 1; js++) tmp[js] = ar_s[js] + k * ar_s[i + 1 - js];
#pragma unroll
        for (int js = 1; js <= i + 1; js++) ar_s[js] = tmp[js];
    }

#pragma unroll
    for (int j = 0; j < 12; j++)
        if (lane == j) ar_out[(size_t)blk * 12 + j] = ar_s[j];
}

// ---------------- invW[f] = sum_{b,kk} |den(b,kk,f)| / |num(b,kk,f)| ----------------
// grid (4, 128): blockIdx.x covers f in chunks of 256, blockIdx.y covers b in chunks of 16
__global__ void invw_kernel(const float* __restrict__ ar, float* __restrict__ invW) {
    __shared__ float sar[16][12];
    const int tid = threadIdx.x;
    const int f = blockIdx.x * 256 + tid;
    const int b0 = blockIdx.y * 16;
    if (tid < 16 * 12) ((float*)sar)[tid] = ar[(size_t)b0 * 12 + tid];
    __syncthreads();

    const float omega = (float)(PI_D / 1024.0) * (float)f;
    float sw, cw;
    __sincosf(omega, &sw, &cw);

    float acc = 0.f;
    for (int bb = 0; bb < 16; bb++) {
        float a0 = sar[bb][0];
        float nr = a0, ni = 0.f, dr = a0, di = 0.f;
        float er = 1.f, ei = 0.f;
        float g1p = 1.f, g2p = 1.f;
#pragma unroll
        for (int j = 1; j < 12; j++) {
            float er2 = er * cw + ei * sw;
            float ei2 = ei * cw - er * sw;
            er = er2; ei = ei2;
            g1p *= 0.92f; g2p *= 0.6f;
            float aj = sar[bb][j];
            float a1 = aj * g1p, a2 = aj * g2p;
            nr += a2 * er; ni += a2 * ei;
            dr += a1 * er; di += a1 * ei;
            acc += sqrtf((dr * dr + di * di) / (nr * nr + ni * ni));
        }
    }
    atomicAdd(&invW[f], acc);
}

// ---------------- build frame matrix A (bf16), rows interleaved x/y ----------------
__global__ void frames_kernel(const float* __restrict__ x, const float* __restrict__ y,
                              __hip_bfloat16* __restrict__ A) {
    const int idx = blockIdx.x * 256 + threadIdx.x;
    const int r = idx >> 11;      // row (frame-pair interleaved)
    const int c = idx & 2047;     // k
    float v = 0.f;
    if (r < MROWS && c < 2046) {
        const int t = r >> 1;
        int p = t * 511 + c - 1023;          // reflect-padded index into signal
        if (p < 0) p = -p;
        else if (p >= L_TOTAL) p = 2 * L_TOTAL - 2 - p;
        v = (r & 1) ? y[p] : x[p];
    }
    A[idx] = __float2bfloat16(v);
}

// ---------------- build DFT basis B^T (bf16) via per-lane rotation recurrence ----------------
// one wave per row; lane handles k = lane + 64j, j<32; rotation step = 64*f*pi/1023
__global__ __launch_bounds__(256) void basis_kernel(__hip_bfloat16* __restrict__ Bt) {
    const int lane = threadIdx.x & 63;
    const int row = blockIdx.x * 4 + (threadIdx.x >> 6);   // 512 blocks -> 2048 rows
    const int f = row >> 1;
    const bool isSin = row & 1;
    const int m0 = (lane * f) % 2046;        // exact angle reduction mod 2pi
    const int md = (64 * f) % 2046;
    float s, c, sd, cd;
    __sincosf((float)m0 * (float)(PI_D / 1023.0), &s, &c);
    __sincosf((float)md * (float)(PI_D / 1023.0), &sd, &cd);
    __hip_bfloat16* out = Bt + (size_t)row * KDIM;
#pragma unroll
    for (int j = 0; j < 32; j++) {
        const int k = lane + 64 * j;
        float v = isSin ? -s : c;
        if (k >= 2046) v = 0.f;
        out[k] = __float2bfloat16(v);
        float c2 = c * cd - s * sd;
        float s2 = s * cd + c * sd;
        c = c2; s = s2;
    }
}

// ---------------- GEMM + fused |X|-|Y| mse epilogue ----------------
// C[M,N] = A[M,K] * Bt[N,K]^T ; 128x128 tile, 4 waves of 4x4 16x16x32 MFMA.
// LDS in MFMA-fragment order: chunk = rowGroup*64 + quad*16 + rowLane
//   -> fragment ds_read_b128s are contiguous 1024B per wave (conflict-free).
// grid (N-tiles=16 fastest, M-tiles=65): consecutive blocks share the A-tile (L2 reuse).
__global__ __launch_bounds__(256) void gemm_mse_kernel(
    const __hip_bfloat16* __restrict__ A, const __hip_bfloat16* __restrict__ Bt,
    float* __restrict__ mse_sum) {
    __shared__ __align__(16) __hip_bfloat16 Al[128 * 32];
    __shared__ __align__(16) __hip_bfloat16 Bl[128 * 32];
    __shared__ float msePart[64];

    const int tid = threadIdx.x;
    const int lane = tid & 63;
    const int w = tid >> 6;
    const int wm = w >> 1, wn = w & 1;
    const int q = lane >> 4, l15 = lane & 15;
    const int tileN = blockIdx.x * 128;
    const int tileM = blockIdx.y * 128;

    floatx4 acc[4][4];
#pragma unroll
    for (int i = 0; i < 4; i++)
#pragma unroll
        for (int j = 0; j < 4; j++) acc[i][j] = (floatx4){0.f, 0.f, 0.f, 0.f};

    // staging: thread tid stages chunk fi = tid (+256); chunk fi holds
    // global (row = (fi>>6)*16 + (fi&15), colChunk = (fi>>4)&3)
    const int rl = tid & 15;
    const int qq = (tid >> 4) & 3;
    const int gg0 = tid >> 6, gg1 = gg0 + 4;
    const size_t offA0 = (size_t)(tileM + gg0 * 16 + rl) * KDIM + qq * 8;
    const size_t offA1 = (size_t)(tileM + gg1 * 16 + rl) * KDIM + qq * 8;
    const size_t offB0 = (size_t)(tileN + gg0 * 16 + rl) * KDIM + qq * 8;
    const size_t offB1 = (size_t)(tileN + gg1 * 16 + rl) * KDIM + qq * 8;
    char* AlB = (char*)Al;
    char* BlB = (char*)Bl;

    for (int kk = 0; kk < KDIM; kk += 32) {
        gld_lds16(A + offA0 + kk, AlB + tid * 16);
        gld_lds16(A + offA1 + kk, AlB + (tid + 256) * 16);
        gld_lds16(Bt + offB0 + kk, BlB + tid * 16);
        gld_lds16(Bt + offB1 + kk, BlB + (tid + 256) * 16);
        __syncthreads();

        short8 af[4], bf[4];
#pragma unroll
        for (int sm = 0; sm < 4; sm++)
            af[sm] = *(const short8*)(AlB + (((wm * 4 + sm) * 64 + lane) * 16));
#pragma unroll
        for (int sn = 0; sn < 4; sn++)
            bf[sn] = *(const short8*)(BlB + (((wn * 4 + sn) * 64 + lane) * 16));
#pragma unroll
        for (int sm = 0; sm < 4; sm++)
#pragma unroll
            for (int sn = 0; sn < 4; sn++)
                acc[sm][sn] = __builtin_amdgcn_mfma_f32_16x16x32_bf16(
                    af[sm], bf[sn], acc[sm][sn], 0, 0, 0);
        __syncthreads();
    }

    // epilogue: C/D layout col=lane&15 (N), row=quad*4+reg (M).
    // even row = X frame, odd row = Y frame; even col = Re, odd col = Im.
    if (tid < 64) msePart[tid] = 0.f;
    __syncthreads();
    const bool evenLane = (l15 & 1) == 0;
#pragma unroll
    for (int sm = 0; sm < 4; sm++) {
#pragma unroll
        for (int sn = 0; sn < 4; sn++) {
#pragma unroll
            for (int rp = 0; rp < 2; rp++) {
                float vE = acc[sm][sn][2 * rp];       // X (even row), this col
                float vO = acc[sm][sn][2 * rp + 1];   // Y (odd row), this col
                float pE = __shfl_xor(vE, 1, 64);     // partner col (Re<->Im)
                float pO = __shfl_xor(vO, 1, 64);
                if (evenLane) {
                    float magX = sqrtf(vE * vE + pE * pE);
                    float magY = sqrtf(vO * vO + pO * pO);
                    float d = magX - magY;
                    int fl = (wn * 64 + sn * 16 + l15) >> 1;
                    atomicAdd(&msePart[fl], d * d);
                }
            }
        }
    }
    __syncthreads();
    if (tid < 64) atomicAdd(&mse_sum[(tileN >> 1) + tid], msePart[tid]);
}

// ---------------- final: out = sum_f mse_sum[f]*invW[f] / (4105*22528*1024) ----------------
__global__ void final_kernel(const float* __restrict__ mse_sum,
                             const float* __restrict__ invW,
                             float* __restrict__ out) {
    __shared__ float red[4];
    const int tid = threadIdx.x;
    float lo = 0.f;
    for (int f = tid; f < 1024; f += 256) lo += mse_sum[f] * invW[f];
    lo = wave_reduce(lo);
    if ((tid & 63) == 0) red[tid >> 6] = lo;
    __syncthreads();
    if (tid == 0) {
        float tot = red[0] + red[1] + red[2] + red[3];
        out[0] = tot * (float)(1.0 / (4105.0 * 22528.0 * 1024.0));
    }
}

extern "C" void kernel_launch(void* const* d_in, const int* in_sizes, int n_in,
                              void* d_out, int out_size, void* d_ws, size_t ws_size,
                              hipStream_t stream) {
    const float* x = (const float*)d_in[0];
    const float* y = (const float*)d_in[1];
    float* out = (float*)d_out;

    float* wsf = (float*)d_ws;
    float* mse_sum = wsf;             // 1024 floats
    float* invW = wsf + 1024;         // 1024 floats
    float* ar = wsf + 2048;           // 2048*12 floats (ends at byte 106496)
    __hip_bfloat16* A = (__hip_bfloat16*)((char*)d_ws + 131072);     // 8320*2048*2 = 34,078,720 B
    __hip_bfloat16* Bt = (__hip_bfloat16*)((char*)d_ws + 34209792);  // 2048*2048*2 = 8,388,608 B

    zero_kernel<<<8, 256, 0, stream>>>(wsf, 2048);
    burg_kernel<<<512, 256, 0, stream>>>(y, ar);
    invw_kernel<<<dim3(4, 128), 256, 0, stream>>>(ar, invW);
    frames_kernel<<<(MPAD * KDIM) / 256, 256, 0, stream>>>(x, y, A);
    basis_kernel<<<512, 256, 0, stream>>>(Bt);
    gemm_mse_kernel<<<dim3(NDIM / 128, MPAD / 128), 256, 0, stream>>>(A, Bt, mse_sum);
    final_kernel<<<1, 256, 0, stream>>>(mse_sum, invW, out);
}

// Round 3
// 233.411 us; speedup vs baseline: 1.3278x; 1.2742x over previous
//
#include <hip/hip_runtime.h>
#include <hip/hip_bf16.h>

#define PI_D 3.14159265358979323846
#define L_TOTAL 2097152
#define NFRAMES 4105      // 1 + L/511
#define MROWS   8210      // 2*NFRAMES (x/y interleaved)
#define MPAD    8320      // 65 * 128
#define KDIM    2048      // 2046 padded
#define NDIM    2048      // 1024 bins * (Re,Im)

// Permuted ("tile-fragment") global layout for A and Bt, in 16B chunks of 8 bf16:
//   chunk16B(row, kc) = (row>>4)*4096 + kc*16 + (row&15),  kc = k/8 in [0,256)
// GEMM staging then reads contiguous 1KB per wave AND LDS lands in MFMA
// fragment order (ds_read_b128 conflict-free, verified round 2).

typedef __attribute__((ext_vector_type(8))) short short8;
typedef __attribute__((ext_vector_type(4))) float floatx4;

typedef __attribute__((address_space(1))) void gvoid_as1;
typedef __attribute__((address_space(3))) void lvoid_as3;

__device__ __forceinline__ void gld_lds16(const void* g, void* l) {
    __builtin_amdgcn_global_load_lds((gvoid_as1*)g, (lvoid_as3*)l, 16, 0, 0);
}

__device__ __forceinline__ float xorall(float v) {
    v += __shfl_xor(v, 1, 64);
    v += __shfl_xor(v, 2, 64);
    v += __shfl_xor(v, 4, 64);
    v += __shfl_xor(v, 8, 64);
    v += __shfl_xor(v, 16, 64);
    v += __shfl_xor(v, 32, 64);
    return v;
}

__device__ __forceinline__ float wave_reduce(float v) {
    v += __shfl_down(v, 32, 64);
    v += __shfl_down(v, 16, 64);
    v += __shfl_down(v, 8, 64);
    v += __shfl_down(v, 4, 64);
    v += __shfl_down(v, 2, 64);
    v += __shfl_down(v, 1, 64);
    return v;
}

// ---------------- Burg LPC: one WAVE per 1024-sample audio block ----------------
// Also zeroes the 2048-float accumulator region (mse_sum + invW) in blocks 0..7.
__global__ __launch_bounds__(256) void burg_kernel(const float* __restrict__ y,
                                                   float* __restrict__ ar_out,
                                                   float* __restrict__ wsf) {
    if (blockIdx.x < 8) wsf[blockIdx.x * 256 + threadIdx.x] = 0.f;

    const int lane = threadIdx.x & 63;
    const int wid = threadIdx.x >> 6;
    const int blk = blockIdx.x * 4 + wid;
    const float* yb = y + (size_t)blk * 1024;

    float f[16], b[16];
#pragma unroll
    for (int r = 0; r < 16; r++) {
        const int idx = r * 64 + lane;
        const bool v = idx < 1023;
        b[r] = v ? yb[idx] : 0.f;
        f[r] = v ? yb[idx + 1] : 0.f;
    }

    float den = 0.f;
#pragma unroll
    for (int r = 0; r < 16; r++) den += f[r] * f[r] + b[r] * b[r];
    den = xorall(den);

    float ar_s[13];
    ar_s[0] = 1.f;
#pragma unroll
    for (int j = 1; j < 13; j++) ar_s[j] = 0.f;

#pragma unroll
    for (int i = 0; i < 12; i++) {
        const int len = 1023 - i;
        float num = 0.f;
#pragma unroll
        for (int r = 0; r < 16; r++) num += f[r] * b[r];
        num = xorall(num);
        const float k = -2.f * num / den;

        float fu[16], bu[16];
#pragma unroll
        for (int r = 0; r < 16; r++) {
            fu[r] = f[r] + k * b[r];
            bu[r] = b[r] + k * f[r];
        }
        const float f0 = __shfl(fu[0], 0, 64);
        const int rr = (len - 1) >> 6;        // == 15 for all i
        const int ll = (len - 1) & 63;        // 62 - i
        const float blast = __shfl(bu[rr], ll, 64);

        // f = fu shifted left by one position (idx -> idx+1); tail stays zero
#pragma unroll
        for (int r = 0; r < 16; r++) {
            float t = __shfl_down(fu[r], 1, 64);
            float w = (r < 15) ? __shfl(fu[r + 1], 0, 64) : 0.f;
            f[r] = (lane == 63) ? w : t;
        }
#pragma unroll
        for (int r = 0; r < 16; r++) b[r] = bu[r];
        if (lane == ll) b[rr] = 0.f;

        den = (1.f - k * k) * den - blast * blast - f0 * f0;

        float tmp[13];
#pragma unroll
        for (int js = 1; js <= i + 1; js++) tmp[js] = ar_s[js] + k * ar_s[i + 1 - js];
#pragma unroll
        for (int js = 1; js <= i + 1; js++) ar_s[js] = tmp[js];
    }

#pragma unroll
    for (int j = 0; j < 12; j++)
        if (lane == j) ar_out[(size_t)blk * 12 + j] = ar_s[j];
}

// ---------------- invW[f] = sum_{b,kk} |den(b,kk,f)| / |num(b,kk,f)| ----------------
__global__ void invw_kernel(const float* __restrict__ ar, float* __restrict__ invW) {
    __shared__ float sar[16][12];
    const int tid = threadIdx.x;
    const int f = blockIdx.x * 256 + tid;
    const int b0 = blockIdx.y * 16;
    if (tid < 16 * 12) ((float*)sar)[tid] = ar[(size_t)b0 * 12 + tid];
    __syncthreads();

    const float omega = (float)(PI_D / 1024.0) * (float)f;
    float sw, cw;
    __sincosf(omega, &sw, &cw);

    float acc = 0.f;
    for (int bb = 0; bb < 16; bb++) {
        float a0 = sar[bb][0];
        float nr = a0, ni = 0.f, dr = a0, di = 0.f;
        float er = 1.f, ei = 0.f;
        float g1p = 1.f, g2p = 1.f;
#pragma unroll
        for (int j = 1; j < 12; j++) {
            float er2 = er * cw + ei * sw;
            float ei2 = ei * cw - er * sw;
            er = er2; ei = ei2;
            g1p *= 0.92f; g2p *= 0.6f;
            float aj = sar[bb][j];
            float a1 = aj * g1p, a2 = aj * g2p;
            nr += a2 * er; ni += a2 * ei;
            dr += a1 * er; di += a1 * ei;
            acc += sqrtf((dr * dr + di * di) / (nr * nr + ni * ni));
        }
    }
    atomicAdd(&invW[f], acc);
}

// ---------------- build frame matrix A (bf16, permuted chunk layout) ----------------
// one thread per 16B chunk; consecutive threads -> consecutive 16B stores.
__global__ __launch_bounds__(256) void frames_kernel(const float* __restrict__ x,
                                                     const float* __restrict__ y,
                                                     __hip_bfloat16* __restrict__ A) {
    const int ci = blockIdx.x * 256 + threadIdx.x;   // chunk index
    const int rb = ci >> 12;
    const int kc = (ci >> 4) & 255;
    const int rowIn = ci & 15;
    const int row = rb * 16 + rowIn;
    __hip_bfloat16 tmp[8];
    if (row < MROWS) {
        const int t = row >> 1;
        const float* src = (row & 1) ? y : x;
        const int base = t * 511 + kc * 8 - 1023;
#pragma unroll
        for (int e = 0; e < 8; e++) {
            const int k = kc * 8 + e;
            float v = 0.f;
            if (k < 2046) {
                int p = base + e;                      // reflect-padded index
                if (p < 0) p = -p;
                else if (p >= L_TOTAL) p = 2 * L_TOTAL - 2 - p;
                v = src[p];
            }
            tmp[e] = __float2bfloat16(v);
        }
    } else {
#pragma unroll
        for (int e = 0; e < 8; e++) tmp[e] = __float2bfloat16(0.f);
    }
    *(short8*)((char*)A + (size_t)ci * 16) = *(short8*)tmp;
}

// ---------------- build DFT basis B^T (bf16, permuted chunk layout) ----------------
// row = 2f (cos) / 2f+1 (-sin); one thread per 16B chunk; exact mod-2046 reduction.
__global__ __launch_bounds__(256) void basis_kernel(__hip_bfloat16* __restrict__ Bt) {
    const int ci = blockIdx.x * 256 + threadIdx.x;
    const int rb = ci >> 12;
    const int kc = (ci >> 4) & 255;
    const int rowIn = ci & 15;
    const int row = rb * 16 + rowIn;
    const int f = row >> 1;
    const bool isSin = row & 1;
    __hip_bfloat16 tmp[8];
#pragma unroll
    for (int e = 0; e < 8; e++) {
        const int k = kc * 8 + e;
        float v = 0.f;
        if (k < 2046) {
            const int m = (k * f) % 2046;            // exact angle mod 2pi
            const float ang = (float)m * (float)(PI_D / 1023.0);
            float s, c;
            __sincosf(ang, &s, &c);
            v = isSin ? -s : c;
        }
        tmp[e] = __float2bfloat16(v);
    }
    *(short8*)((char*)Bt + (size_t)ci * 16) = *(short8*)tmp;
}

// ---------------- GEMM + fused |X|-|Y| mse epilogue ----------------
// C[M,N] = A[M,K]*Bt[N,K]^T; 128x128 tile, 4 waves of 4x4 16x16x32 MFMA.
// Permuted global layout => each wave's global_load_lds covers a contiguous
// 1KB run (full coalescing) and LDS is in fragment order (0 bank conflicts).
__global__ __launch_bounds__(256) void gemm_mse_kernel(
    const __hip_bfloat16* __restrict__ A, const __hip_bfloat16* __restrict__ Bt,
    float* __restrict__ mse_sum) {
    __shared__ __align__(16) __hip_bfloat16 Al[128 * 32];
    __shared__ __align__(16) __hip_bfloat16 Bl[128 * 32];
    __shared__ float msePart[64];

    const int tid = threadIdx.x;
    const int lane = tid & 63;
    const int w = tid >> 6;
    const int wm = w >> 1, wn = w & 1;
    const int l15 = lane & 15;
    const int tileN = blockIdx.x * 128;
    const int tileM = blockIdx.y * 128;

    floatx4 acc[4][4];
#pragma unroll
    for (int i = 0; i < 4; i++)
#pragma unroll
        for (int j = 0; j < 4; j++) acc[i][j] = (floatx4){0.f, 0.f, 0.f, 0.f};

    // staging: thread tid stages LDS chunks tid and tid+256.
    // global chunk16B at kk=0: ((tileM>>4)+gg)*4096 + qq*16 + rl == base + lane (contiguous!)
    const int rl = tid & 15;
    const int qq = (tid >> 4) & 3;
    const int gg0 = tid >> 6;
    const char* pA0 = (const char*)A + ((((size_t)(tileM >> 4) + gg0) << 12) + qq * 16 + rl) * 16;
    const char* pA1 = pA0 + (size_t)4 * 4096 * 16;
    const char* pB0 = (const char*)Bt + ((((size_t)(tileN >> 4) + gg0) << 12) + qq * 16 + rl) * 16;
    const char* pB1 = pB0 + (size_t)4 * 4096 * 16;
    char* AlB = (char*)Al;
    char* BlB = (char*)Bl;

    for (int it = 0; it < KDIM / 32; it++) {
        gld_lds16(pA0, AlB + tid * 16);
        gld_lds16(pA1, AlB + (tid + 256) * 16);
        gld_lds16(pB0, BlB + tid * 16);
        gld_lds16(pB1, BlB + (tid + 256) * 16);
        pA0 += 1024; pA1 += 1024; pB0 += 1024; pB1 += 1024;  // 64 chunks per K-step of 32
        __syncthreads();

        short8 af[4], bf[4];
#pragma unroll
        for (int sm = 0; sm < 4; sm++)
            af[sm] = *(const short8*)(AlB + (((wm * 4 + sm) * 64 + lane) * 16));
#pragma unroll
        for (int sn = 0; sn < 4; sn++)
            bf[sn] = *(const short8*)(BlB + (((wn * 4 + sn) * 64 + lane) * 16));
#pragma unroll
        for (int sm = 0; sm < 4; sm++)
#pragma unroll
            for (int sn = 0; sn < 4; sn++)
                acc[sm][sn] = __builtin_amdgcn_mfma_f32_16x16x32_bf16(
                    af[sm], bf[sn], acc[sm][sn], 0, 0, 0);
        __syncthreads();
    }

    // epilogue: C/D layout col=lane&15 (N), row=quad*4+reg (M).
    // even row = X frame, odd row = Y frame; even col = Re, odd col = Im.
    if (tid < 64) msePart[tid] = 0.f;
    __syncthreads();
    const bool evenLane = (l15 & 1) == 0;
#pragma unroll
    for (int sm = 0; sm < 4; sm++) {
#pragma unroll
        for (int sn = 0; sn < 4; sn++) {
#pragma unroll
            for (int rp = 0; rp < 2; rp++) {
                float vE = acc[sm][sn][2 * rp];       // X (even row), this col
                float vO = acc[sm][sn][2 * rp + 1];   // Y (odd row), this col
                float pE = __shfl_xor(vE, 1, 64);     // partner col (Re<->Im)
                float pO = __shfl_xor(vO, 1, 64);
                if (evenLane) {
                    float magX = sqrtf(vE * vE + pE * pE);
                    float magY = sqrtf(vO * vO + pO * pO);
                    float d = magX - magY;
                    int fl = (wn * 64 + sn * 16 + l15) >> 1;
                    atomicAdd(&msePart[fl], d * d);
                }
            }
        }
    }
    __syncthreads();
    if (tid < 64) atomicAdd(&mse_sum[(tileN >> 1) + tid], msePart[tid]);
}

// ---------------- final: out = sum_f mse_sum[f]*invW[f] / (4105*22528*1024) ----------------
__global__ void final_kernel(const float* __restrict__ mse_sum,
                             const float* __restrict__ invW,
                             float* __restrict__ out) {
    __shared__ float red[4];
    const int tid = threadIdx.x;
    float lo = 0.f;
    for (int f = tid; f < 1024; f += 256) lo += mse_sum[f] * invW[f];
    lo = wave_reduce(lo);
    if ((tid & 63) == 0) red[tid >> 6] = lo;
    __syncthreads();
    if (tid == 0) {
        float tot = red[0] + red[1] + red[2] + red[3];
        out[0] = tot * (float)(1.0 / (4105.0 * 22528.0 * 1024.0));
    }
}

extern "C" void kernel_launch(void* const* d_in, const int* in_sizes, int n_in,
                              void* d_out, int out_size, void* d_ws, size_t ws_size,
                              hipStream_t stream) {
    const float* x = (const float*)d_in[0];
    const float* y = (const float*)d_in[1];
    float* out = (float*)d_out;

    float* wsf = (float*)d_ws;
    float* mse_sum = wsf;             // 1024 floats
    float* invW = wsf + 1024;         // 1024 floats
    float* ar = wsf + 2048;           // 2048*12 floats (ends at byte 106496)
    __hip_bfloat16* A = (__hip_bfloat16*)((char*)d_ws + 131072);     // 8320*2048*2 B (permuted)
    __hip_bfloat16* Bt = (__hip_bfloat16*)((char*)d_ws + 34209792);  // 2048*2048*2 B (permuted)

    burg_kernel<<<512, 256, 0, stream>>>(y, ar, wsf);
    invw_kernel<<<dim3(4, 128), 256, 0, stream>>>(ar, invW);
    frames_kernel<<<MPAD * 256 / 256, 256, 0, stream>>>(x, y, A);   // 8320 blocks
    basis_kernel<<<NDIM * 256 / 256, 256, 0, stream>>>(Bt);         // 2048 blocks
    gemm_mse_kernel<<<dim3(NDIM / 128, MPAD / 128), 256, 0, stream>>>(A, Bt, mse_sum);
    final_kernel<<<1, 256, 0, stream>>>(mse_sum, invW, out);
}

// Round 4
// 232.394 us; speedup vs baseline: 1.3336x; 1.0044x over previous
//
#include <hip/hip_runtime.h>
#include <hip/hip_bf16.h>

#define PI_D 3.14159265358979323846
#define L_TOTAL 2097152
#define NFRAMES 4105      // 1 + L/511
#define MROWS   8210      // 2*NFRAMES (x/y interleaved)
#define MPAD    8320      // 65 * 128
#define KDIM    2048      // 2046 padded
#define NDIM    2048      // 1024 bins * (Re,Im)

// Permuted ("tile-fragment") global layout for A and Bt, in 16B chunks of 8 bf16:
//   chunk16B(row, kc) = (row>>4)*4096 + kc*16 + (row&15),  kc = k/8 in [0,256)
// GEMM staging reads contiguous 1KB per wave AND LDS lands in MFMA fragment
// order (ds_read_b128 conflict-free; verified rounds 2-3).

typedef __attribute__((ext_vector_type(8))) short short8;
typedef __attribute__((ext_vector_type(4))) float floatx4;

typedef __attribute__((address_space(1))) void gvoid_as1;
typedef __attribute__((address_space(3))) void lvoid_as3;

__device__ __forceinline__ void gld_lds16(const void* g, void* l) {
    __builtin_amdgcn_global_load_lds((gvoid_as1*)g, (lvoid_as3*)l, 16, 0, 0);
}

__device__ __forceinline__ float xorall(float v) {
    v += __shfl_xor(v, 1, 64);
    v += __shfl_xor(v, 2, 64);
    v += __shfl_xor(v, 4, 64);
    v += __shfl_xor(v, 8, 64);
    v += __shfl_xor(v, 16, 64);
    v += __shfl_xor(v, 32, 64);
    return v;
}

__device__ __forceinline__ float wave_reduce(float v) {
    v += __shfl_down(v, 32, 64);
    v += __shfl_down(v, 16, 64);
    v += __shfl_down(v, 8, 64);
    v += __shfl_down(v, 4, 64);
    v += __shfl_down(v, 2, 64);
    v += __shfl_down(v, 1, 64);
    return v;
}

// ---------------- Burg LPC: one WAVE per 1024-sample audio block ----------------
// Lane-contiguous layout: lane l holds positions l*16 .. l*16+15. Shift-by-1 is
// an in-lane rotate + one shfl_down (boundary). Also zeroes accumulators.
__global__ __launch_bounds__(256) void burg_kernel(const float* __restrict__ y,
                                                   float* __restrict__ ar_out,
                                                   float* __restrict__ wsf) {
    if (blockIdx.x < 8) wsf[blockIdx.x * 256 + threadIdx.x] = 0.f;

    const int lane = threadIdx.x & 63;
    const int wid = threadIdx.x >> 6;
    const int blk = blockIdx.x * 4 + wid;
    const float4* yb4 = (const float4*)(y + (size_t)blk * 1024) + lane * 4;

    float t[16];
#pragma unroll
    for (int q = 0; q < 4; q++) {
        float4 v = yb4[q];
        t[q * 4 + 0] = v.x; t[q * 4 + 1] = v.y;
        t[q * 4 + 2] = v.z; t[q * 4 + 3] = v.w;
    }
    // b[pos] = y[pos] (pos<=1022), f[pos] = y[pos+1] (pos<=1022); pos 1023 = 0
    float b[16], f[16];
#pragma unroll
    for (int r = 0; r < 16; r++) b[r] = t[r];
#pragma unroll
    for (int r = 0; r < 15; r++) f[r] = t[r + 1];
    {
        float nb = __shfl_down(t[0], 1, 64);
        f[15] = (lane == 63) ? 0.f : nb;
        if (lane == 63) b[15] = 0.f;
    }

    float den = 0.f;
#pragma unroll
    for (int r = 0; r < 16; r++) den += f[r] * f[r] + b[r] * b[r];
    den = xorall(den);

    float ar_s[13];
    ar_s[0] = 1.f;
#pragma unroll
    for (int j = 1; j < 13; j++) ar_s[j] = 0.f;

#pragma unroll
    for (int i = 0; i < 12; i++) {
        float num = 0.f;
#pragma unroll
        for (int r = 0; r < 16; r++) num += f[r] * b[r];
        num = xorall(num);
        const float k = -2.f * num / den;

        float fu[16], bu[16];
#pragma unroll
        for (int r = 0; r < 16; r++) {
            fu[r] = f[r] + k * b[r];
            bu[r] = b[r] + k * f[r];
        }
        const float f0 = __shfl(fu[0], 0, 64);
        const int pos = 1022 - i;               // last valid b position
        const int L = pos >> 4, S = pos & 15;   // compile-time per unrolled i
        const float blast = __shfl(bu[S], L, 64);

        den = (1.f - k * k) * den - blast * blast - f0 * f0;

        // f = fu shifted left by 1 (in-lane rotate + boundary shuffle)
        float nf = __shfl_down(fu[0], 1, 64);
#pragma unroll
        for (int r = 0; r < 15; r++) f[r] = fu[r + 1];
        f[15] = (lane == 63) ? 0.f : nf;
        // b = bu with position pos zeroed
#pragma unroll
        for (int r = 0; r < 16; r++) b[r] = bu[r];
        if (lane == L) b[S] = 0.f;

        float tmp[13];
#pragma unroll
        for (int js = 1; js <= i + 1; js++) tmp[js] = ar_s[js] + k * ar_s[i + 1 - js];
#pragma unroll
        for (int js = 1; js <= i + 1; js++) ar_s[js] = tmp[js];
    }

#pragma unroll
    for (int j = 0; j < 12; j++)
        if (lane == j) ar_out[(size_t)blk * 12 + j] = ar_s[j];
}

// ---------------- invW[f] = sum_{b,kk} |den(b,kk,f)| / |num(b,kk,f)| ----------------
__global__ void invw_kernel(const float* __restrict__ ar, float* __restrict__ invW) {
    __shared__ float sar[16][12];
    const int tid = threadIdx.x;
    const int f = blockIdx.x * 256 + tid;
    const int b0 = blockIdx.y * 16;
    if (tid < 16 * 12) ((float*)sar)[tid] = ar[(size_t)b0 * 12 + tid];
    __syncthreads();

    const float omega = (float)(PI_D / 1024.0) * (float)f;
    float sw, cw;
    __sincosf(omega, &sw, &cw);

    float acc = 0.f;
    for (int bb = 0; bb < 16; bb++) {
        float a0 = sar[bb][0];
        float nr = a0, ni = 0.f, dr = a0, di = 0.f;
        float er = 1.f, ei = 0.f;
        float g1p = 1.f, g2p = 1.f;
#pragma unroll
        for (int j = 1; j < 12; j++) {
            float er2 = er * cw + ei * sw;
            float ei2 = ei * cw - er * sw;
            er = er2; ei = ei2;
            g1p *= 0.92f; g2p *= 0.6f;
            float aj = sar[bb][j];
            float a1 = aj * g1p, a2 = aj * g2p;
            nr += a2 * er; ni += a2 * ei;
            dr += a1 * er; di += a1 * ei;
            // sqrt(D/N) = D * rsq(D*N)
            float D = dr * dr + di * di;
            float Nn = nr * nr + ni * ni;
            acc += D * __builtin_amdgcn_rsqf(D * Nn);
        }
    }
    atomicAdd(&invW[f], acc);
}

// ---------------- build frame matrix A (bf16, permuted chunk layout) ----------------
__global__ __launch_bounds__(256) void frames_kernel(const float* __restrict__ x,
                                                     const float* __restrict__ y,
                                                     __hip_bfloat16* __restrict__ A) {
    const int ci = blockIdx.x * 256 + threadIdx.x;   // chunk index
    const int rb = ci >> 12;
    const int kc = (ci >> 4) & 255;
    const int rowIn = ci & 15;
    const int row = rb * 16 + rowIn;
    __hip_bfloat16 tmp[8];
    if (row < MROWS) {
        const int t = row >> 1;
        const float* src = (row & 1) ? y : x;
        const int base = t * 511 + kc * 8 - 1023;
#pragma unroll
        for (int e = 0; e < 8; e++) {
            const int k = kc * 8 + e;
            float v = 0.f;
            if (k < 2046) {
                int p = base + e;                      // reflect-padded index
                if (p < 0) p = -p;
                else if (p >= L_TOTAL) p = 2 * L_TOTAL - 2 - p;
                v = src[p];
            }
            tmp[e] = __float2bfloat16(v);
        }
    } else {
#pragma unroll
        for (int e = 0; e < 8; e++) tmp[e] = __float2bfloat16(0.f);
    }
    *(short8*)((char*)A + (size_t)ci * 16) = *(short8*)tmp;
}

// ---------------- build DFT basis B^T (bf16, permuted chunk layout) ----------------
__global__ __launch_bounds__(256) void basis_kernel(__hip_bfloat16* __restrict__ Bt) {
    const int ci = blockIdx.x * 256 + threadIdx.x;
    const int rb = ci >> 12;
    const int kc = (ci >> 4) & 255;
    const int rowIn = ci & 15;
    const int row = rb * 16 + rowIn;
    const int f = row >> 1;
    const bool isSin = row & 1;
    __hip_bfloat16 tmp[8];
#pragma unroll
    for (int e = 0; e < 8; e++) {
        const int k = kc * 8 + e;
        float v = 0.f;
        if (k < 2046) {
            const int m = (k * f) % 2046;            // exact angle mod 2pi
            const float ang = (float)m * (float)(PI_D / 1023.0);
            float s, c;
            __sincosf(ang, &s, &c);
            v = isSin ? -s : c;
        }
        tmp[e] = __float2bfloat16(v);
    }
    *(short8*)((char*)Bt + (size_t)ci * 16) = *(short8*)tmp;
}

// ---------------- GEMM + fused |X|-|Y| mse epilogue (BK=64) ----------------
// C[M,N] = A[M,K]*Bt[N,K]^T; 128x128 tile, 4 waves of 4x4 16x16x32 MFMA.
// BK=64 halves the barrier count vs BK=32 (32 K-iters). LDS 2x16KB.
__global__ __launch_bounds__(256) void gemm_mse_kernel(
    const __hip_bfloat16* __restrict__ A, const __hip_bfloat16* __restrict__ Bt,
    float* __restrict__ mse_sum) {
    __shared__ __align__(16) __hip_bfloat16 Al[128 * 64];
    __shared__ __align__(16) __hip_bfloat16 Bl[128 * 64];
    __shared__ float msePart[64];

    const int tid = threadIdx.x;
    const int lane = tid & 63;
    const int w = tid >> 6;
    const int wm = w >> 1, wn = w & 1;
    const int l15 = lane & 15;
    const int tileN = blockIdx.x * 128;
    const int tileM = blockIdx.y * 128;

    floatx4 acc[4][4];
#pragma unroll
    for (int i = 0; i < 4; i++)
#pragma unroll
        for (int j = 0; j < 4; j++) acc[i][j] = (floatx4){0.f, 0.f, 0.f, 0.f};

    // staging: per iter, 1024 chunks per matrix; round rr: thread stages local
    // chunk rr*256+tid. gg = (rr*256+tid)>>7 = 2*rr + (tid>>7); inner = tid&127.
    // global byte = ((tileM>>4)+gg)*65536 + it*2048 + inner*16  -> pA0 + rr*131072
    const int hi = tid >> 7;
    const int inner = tid & 127;
    const char* pA0 = (const char*)A + (((size_t)(tileM >> 4) + hi) << 16) + inner * 16;
    const char* pB0 = (const char*)Bt + (((size_t)(tileN >> 4) + hi) << 16) + inner * 16;
    char* AlB = (char*)Al;
    char* BlB = (char*)Bl;

    for (int it = 0; it < KDIM / 64; it++) {
#pragma unroll
        for (int rr = 0; rr < 4; rr++)
            gld_lds16(pA0 + rr * 131072, AlB + tid * 16 + rr * 4096);
#pragma unroll
        for (int rr = 0; rr < 4; rr++)
            gld_lds16(pB0 + rr * 131072, BlB + tid * 16 + rr * 4096);
        pA0 += 2048; pB0 += 2048;
        __syncthreads();

#pragma unroll
        for (int ks = 0; ks < 2; ks++) {
            short8 af[4], bf[4];
#pragma unroll
            for (int sm = 0; sm < 4; sm++)
                af[sm] = *(const short8*)(AlB + (wm * 4 + sm) * 2048 + ks * 1024 + lane * 16);
#pragma unroll
            for (int sn = 0; sn < 4; sn++)
                bf[sn] = *(const short8*)(BlB + (wn * 4 + sn) * 2048 + ks * 1024 + lane * 16);
#pragma unroll
            for (int sm = 0; sm < 4; sm++)
#pragma unroll
                for (int sn = 0; sn < 4; sn++)
                    acc[sm][sn] = __builtin_amdgcn_mfma_f32_16x16x32_bf16(
                        af[sm], bf[sn], acc[sm][sn], 0, 0, 0);
        }
        __syncthreads();
    }

    // epilogue: C/D layout col=lane&15 (N), row=quad*4+reg (M).
    // even row = X frame, odd row = Y frame; even col = Re, odd col = Im.
    if (tid < 64) msePart[tid] = 0.f;
    __syncthreads();
    const bool evenLane = (l15 & 1) == 0;
#pragma unroll
    for (int sm = 0; sm < 4; sm++) {
#pragma unroll
        for (int sn = 0; sn < 4; sn++) {
#pragma unroll
            for (int rp = 0; rp < 2; rp++) {
                float vE = acc[sm][sn][2 * rp];       // X (even row), this col
                float vO = acc[sm][sn][2 * rp + 1];   // Y (odd row), this col
                float pE = __shfl_xor(vE, 1, 64);     // partner col (Re<->Im)
                float pO = __shfl_xor(vO, 1, 64);
                if (evenLane) {
                    float magX = sqrtf(vE * vE + pE * pE);
                    float magY = sqrtf(vO * vO + pO * pO);
                    float d = magX - magY;
                    int fl = (wn * 64 + sn * 16 + l15) >> 1;
                    atomicAdd(&msePart[fl], d * d);
                }
            }
        }
    }
    __syncthreads();
    if (tid < 64) atomicAdd(&mse_sum[(tileN >> 1) + tid], msePart[tid]);
}

// ---------------- final: out = sum_f mse_sum[f]*invW[f] / (4105*22528*1024) ----------------
__global__ void final_kernel(const float* __restrict__ mse_sum,
                             const float* __restrict__ invW,
                             float* __restrict__ out) {
    __shared__ float red[4];
    const int tid = threadIdx.x;
    float lo = 0.f;
    for (int f = tid; f < 1024; f += 256) lo += mse_sum[f] * invW[f];
    lo = wave_reduce(lo);
    if ((tid & 63) == 0) red[tid >> 6] = lo;
    __syncthreads();
    if (tid == 0) {
        float tot = red[0] + red[1] + red[2] + red[3];
        out[0] = tot * (float)(1.0 / (4105.0 * 22528.0 * 1024.0));
    }
}

extern "C" void kernel_launch(void* const* d_in, const int* in_sizes, int n_in,
                              void* d_out, int out_size, void* d_ws, size_t ws_size,
                              hipStream_t stream) {
    const float* x = (const float*)d_in[0];
    const float* y = (const float*)d_in[1];
    float* out = (float*)d_out;

    float* wsf = (float*)d_ws;
    float* mse_sum = wsf;             // 1024 floats
    float* invW = wsf + 1024;         // 1024 floats
    float* ar = wsf + 2048;           // 2048*12 floats (ends at byte 106496)
    __hip_bfloat16* A = (__hip_bfloat16*)((char*)d_ws + 131072);     // 8320*2048*2 B (permuted)
    __hip_bfloat16* Bt = (__hip_bfloat16*)((char*)d_ws + 34209792);  // 2048*2048*2 B (permuted)

    burg_kernel<<<512, 256, 0, stream>>>(y, ar, wsf);
    invw_kernel<<<dim3(4, 128), 256, 0, stream>>>(ar, invW);
    frames_kernel<<<8320, 256, 0, stream>>>(x, y, A);
    basis_kernel<<<2048, 256, 0, stream>>>(Bt);
    gemm_mse_kernel<<<dim3(NDIM / 128, MPAD / 128), 256, 0, stream>>>(A, Bt, mse_sum);
    final_kernel<<<1, 256, 0, stream>>>(mse_sum, invW, out);
}

// Round 5
// 229.586 us; speedup vs baseline: 1.3499x; 1.0122x over previous
//
#include <hip/hip_runtime.h>
#include <hip/hip_bf16.h>

#define PI_D 3.14159265358979323846
#define L_TOTAL 2097152
#define NFRAMES 4105      // 1 + L/511
#define MROWS   8210      // 2*NFRAMES (x/y interleaved)
#define MPAD    8320      // 65 * 128
#define KDIM    2048      // 2046 padded
#define NDIM    2048      // 1024 bins * (Re,Im)

// Permuted ("tile-fragment") global layout for A and Bt, in 16B chunks of 8 bf16:
//   chunk16B(row, kc) = (row>>4)*4096 + kc*16 + (row&15),  kc = k/8 in [0,256)
// GEMM staging reads contiguous 1KB per wave AND LDS lands in MFMA fragment
// order (ds_read_b128 conflict-free; verified rounds 2-3).

#define FRAMES_BLOCKS 8320
#define BASIS_BLOCKS  2048
#define BURG_BLOCKS   512
#define PREP_BLOCKS   (FRAMES_BLOCKS + BASIS_BLOCKS + BURG_BLOCKS)

typedef __attribute__((ext_vector_type(8))) short short8;
typedef __attribute__((ext_vector_type(4))) float floatx4;

typedef __attribute__((address_space(1))) void gvoid_as1;
typedef __attribute__((address_space(3))) void lvoid_as3;

__device__ __forceinline__ void gld_lds16(const void* g, void* l) {
    __builtin_amdgcn_global_load_lds((gvoid_as1*)g, (lvoid_as3*)l, 16, 0, 0);
}

__device__ __forceinline__ float xorall(float v) {
    v += __shfl_xor(v, 1, 64);
    v += __shfl_xor(v, 2, 64);
    v += __shfl_xor(v, 4, 64);
    v += __shfl_xor(v, 8, 64);
    v += __shfl_xor(v, 16, 64);
    v += __shfl_xor(v, 32, 64);
    return v;
}

__device__ __forceinline__ float wave_reduce(float v) {
    v += __shfl_down(v, 32, 64);
    v += __shfl_down(v, 16, 64);
    v += __shfl_down(v, 8, 64);
    v += __shfl_down(v, 4, 64);
    v += __shfl_down(v, 2, 64);
    v += __shfl_down(v, 1, 64);
    return v;
}

// ---------------- frames branch: build A (bf16, permuted chunk layout) ----------------
// lane remap: 16-lane group covers 16 consecutive kc of ONE row -> contiguous
// 512B source reads; stores are 64B-line-complete within the wave.
__device__ __forceinline__ void frames_body(int bid, int tid,
                                            const float* __restrict__ x,
                                            const float* __restrict__ y,
                                            __hip_bfloat16* __restrict__ A) {
    const int rb = bid >> 4;
    const int kcHi = bid & 15;
    const int kcLo = tid & 15;
    const int rowIn = tid >> 4;
    const int kc = kcHi * 16 + kcLo;
    const int row = rb * 16 + rowIn;
    const int ci = bid * 256 + kcLo * 16 + rowIn;    // == rb*4096 + kc*16 + rowIn
    __hip_bfloat16 tmp[8];
    if (row < MROWS) {
        const int t = row >> 1;
        const float* src = (row & 1) ? y : x;
        const int base = t * 511 + kc * 8 - 1023;
#pragma unroll
        for (int e = 0; e < 8; e++) {
            const int k = kc * 8 + e;
            float v = 0.f;
            if (k < 2046) {
                int p = base + e;                      // reflect-padded index
                if (p < 0) p = -p;
                else if (p >= L_TOTAL) p = 2 * L_TOTAL - 2 - p;
                v = src[p];
            }
            tmp[e] = __float2bfloat16(v);
        }
    } else {
#pragma unroll
        for (int e = 0; e < 8; e++) tmp[e] = __float2bfloat16(0.f);
    }
    *(short8*)((char*)A + (size_t)ci * 16) = *(short8*)tmp;
}

// ---------------- basis branch: B^T (bf16, permuted chunk layout) ----------------
__device__ __forceinline__ void basis_body(int bid, int tid,
                                           __hip_bfloat16* __restrict__ Bt) {
    const int ci = bid * 256 + tid;
    const int rb = ci >> 12;
    const int kc = (ci >> 4) & 255;
    const int rowIn = ci & 15;
    const int row = rb * 16 + rowIn;
    const int f = row >> 1;
    const bool isSin = row & 1;
    __hip_bfloat16 tmp[8];
#pragma unroll
    for (int e = 0; e < 8; e++) {
        const int k = kc * 8 + e;
        float v = 0.f;
        if (k < 2046) {
            const int m = (k * f) % 2046;            // exact angle mod 2pi
            const float ang = (float)m * (float)(PI_D / 1023.0);
            float s, c;
            __sincosf(ang, &s, &c);
            v = isSin ? -s : c;
        }
        tmp[e] = __float2bfloat16(v);
    }
    *(short8*)((char*)Bt + (size_t)ci * 16) = *(short8*)tmp;
}

// ---------------- burg branch: one WAVE per 1024-sample audio block ----------------
__device__ __forceinline__ void burg_body(int bid, int tid,
                                          const float* __restrict__ y,
                                          float* __restrict__ ar_out,
                                          float* __restrict__ wsf) {
    if (bid < 8) wsf[bid * 256 + tid] = 0.f;

    const int lane = tid & 63;
    const int wid = tid >> 6;
    const int blk = bid * 4 + wid;
    const float4* yb4 = (const float4*)(y + (size_t)blk * 1024) + lane * 4;

    float t[16];
#pragma unroll
    for (int q = 0; q < 4; q++) {
        float4 v = yb4[q];
        t[q * 4 + 0] = v.x; t[q * 4 + 1] = v.y;
        t[q * 4 + 2] = v.z; t[q * 4 + 3] = v.w;
    }
    float b[16], f[16];
#pragma unroll
    for (int r = 0; r < 16; r++) b[r] = t[r];
#pragma unroll
    for (int r = 0; r < 15; r++) f[r] = t[r + 1];
    {
        float nb = __shfl_down(t[0], 1, 64);
        f[15] = (lane == 63) ? 0.f : nb;
        if (lane == 63) b[15] = 0.f;
    }

    float den = 0.f;
#pragma unroll
    for (int r = 0; r < 16; r++) den += f[r] * f[r] + b[r] * b[r];
    den = xorall(den);

    float ar_s[13];
    ar_s[0] = 1.f;
#pragma unroll
    for (int j = 1; j < 13; j++) ar_s[j] = 0.f;

#pragma unroll
    for (int i = 0; i < 12; i++) {
        float num = 0.f;
#pragma unroll
        for (int r = 0; r < 16; r++) num += f[r] * b[r];
        num = xorall(num);
        const float k = -2.f * num / den;

        float fu[16], bu[16];
#pragma unroll
        for (int r = 0; r < 16; r++) {
            fu[r] = f[r] + k * b[r];
            bu[r] = b[r] + k * f[r];
        }
        const float f0 = __shfl(fu[0], 0, 64);
        const int pos = 1022 - i;               // last valid b position
        const int L = pos >> 4, S = pos & 15;   // compile-time per unrolled i
        const float blast = __shfl(bu[S], L, 64);

        den = (1.f - k * k) * den - blast * blast - f0 * f0;

        float nf = __shfl_down(fu[0], 1, 64);
#pragma unroll
        for (int r = 0; r < 15; r++) f[r] = fu[r + 1];
        f[15] = (lane == 63) ? 0.f : nf;
#pragma unroll
        for (int r = 0; r < 16; r++) b[r] = bu[r];
        if (lane == L) b[S] = 0.f;

        float tmp[13];
#pragma unroll
        for (int js = 1; js <= i + 1; js++) tmp[js] = ar_s[js] + k * ar_s[i + 1 - js];
#pragma unroll
        for (int js = 1; js <= i + 1; js++) ar_s[js] = tmp[js];
    }

#pragma unroll
    for (int j = 0; j < 12; j++)
        if (lane == j) ar_out[(size_t)blk * 12 + j] = ar_s[j];
}

// ---------------- fused prep: frames | basis | burg (independent) ----------------
__global__ __launch_bounds__(256) void prep_kernel(const float* __restrict__ x,
                                                   const float* __restrict__ y,
                                                   __hip_bfloat16* __restrict__ A,
                                                   __hip_bfloat16* __restrict__ Bt,
                                                   float* __restrict__ ar,
                                                   float* __restrict__ wsf) {
    const int bid = blockIdx.x;
    const int tid = threadIdx.x;
    if (bid < FRAMES_BLOCKS) {
        frames_body(bid, tid, x, y, A);
    } else if (bid < FRAMES_BLOCKS + BASIS_BLOCKS) {
        basis_body(bid - FRAMES_BLOCKS, tid, Bt);
    } else {
        burg_body(bid - FRAMES_BLOCKS - BASIS_BLOCKS, tid, y, ar, wsf);
    }
}

// ---------------- invW[f] = sum_{b,kk} |den(b,kk,f)| / |num(b,kk,f)| ----------------
__global__ __launch_bounds__(256) void invw_kernel(const float* __restrict__ ar,
                                                   float* __restrict__ invW) {
    __shared__ float sar[16][12];
    const int tid = threadIdx.x;
    const int f = blockIdx.x * 256 + tid;
    const int b0 = blockIdx.y * 16;
    if (tid < 16 * 12) ((float*)sar)[tid] = ar[(size_t)b0 * 12 + tid];
    __syncthreads();

    const float omega = (float)(PI_D / 1024.0) * (float)f;
    float sw, cw;
    __sincosf(omega, &sw, &cw);

    float acc = 0.f;
#pragma unroll 4
    for (int bb = 0; bb < 16; bb++) {
        float a0 = sar[bb][0];
        float nr = a0, ni = 0.f, dr = a0, di = 0.f;
        float er = 1.f, ei = 0.f;
        float g1p = 1.f, g2p = 1.f;
#pragma unroll
        for (int j = 1; j < 12; j++) {
            float er2 = er * cw + ei * sw;
            float ei2 = ei * cw - er * sw;
            er = er2; ei = ei2;
            g1p *= 0.92f; g2p *= 0.6f;
            float aj = sar[bb][j];
            float a1 = aj * g1p, a2 = aj * g2p;
            nr += a2 * er; ni += a2 * ei;
            dr += a1 * er; di += a1 * ei;
            // sqrt(D/N) = D * rsq(D*N)
            float D = dr * dr + di * di;
            float Nn = nr * nr + ni * ni;
            acc += D * __builtin_amdgcn_rsqf(D * Nn);
        }
    }
    atomicAdd(&invW[f], acc);
}

// ---------------- GEMM + fused |X|-|Y| mse epilogue (BK=32, proven) ----------------
// C[M,N] = A[M,K]*Bt[N,K]^T; 128x128 tile, 4 waves of 4x4 16x16x32 MFMA.
// Permuted global layout => each wave's global_load_lds covers a contiguous
// 1KB run (full coalescing) and LDS is in fragment order (0 bank conflicts).
__global__ __launch_bounds__(256) void gemm_mse_kernel(
    const __hip_bfloat16* __restrict__ A, const __hip_bfloat16* __restrict__ Bt,
    float* __restrict__ mse_sum) {
    __shared__ __align__(16) __hip_bfloat16 Al[128 * 32];
    __shared__ __align__(16) __hip_bfloat16 Bl[128 * 32];
    __shared__ float msePart[64];

    const int tid = threadIdx.x;
    const int lane = tid & 63;
    const int w = tid >> 6;
    const int wm = w >> 1, wn = w & 1;
    const int l15 = lane & 15;
    const int tileN = blockIdx.x * 128;
    const int tileM = blockIdx.y * 128;

    floatx4 acc[4][4];
#pragma unroll
    for (int i = 0; i < 4; i++)
#pragma unroll
        for (int j = 0; j < 4; j++) acc[i][j] = (floatx4){0.f, 0.f, 0.f, 0.f};

    const int rl = tid & 15;
    const int qq = (tid >> 4) & 3;
    const int gg0 = tid >> 6;
    const char* pA0 = (const char*)A + ((((size_t)(tileM >> 4) + gg0) << 12) + qq * 16 + rl) * 16;
    const char* pA1 = pA0 + (size_t)4 * 4096 * 16;
    const char* pB0 = (const char*)Bt + ((((size_t)(tileN >> 4) + gg0) << 12) + qq * 16 + rl) * 16;
    const char* pB1 = pB0 + (size_t)4 * 4096 * 16;
    char* AlB = (char*)Al;
    char* BlB = (char*)Bl;

    for (int it = 0; it < KDIM / 32; it++) {
        gld_lds16(pA0, AlB + tid * 16);
        gld_lds16(pA1, AlB + (tid + 256) * 16);
        gld_lds16(pB0, BlB + tid * 16);
        gld_lds16(pB1, BlB + (tid + 256) * 16);
        pA0 += 1024; pA1 += 1024; pB0 += 1024; pB1 += 1024;  // 64 chunks per K-step of 32
        __syncthreads();

        short8 af[4], bf[4];
#pragma unroll
        for (int sm = 0; sm < 4; sm++)
            af[sm] = *(const short8*)(AlB + (((wm * 4 + sm) * 64 + lane) * 16));
#pragma unroll
        for (int sn = 0; sn < 4; sn++)
            bf[sn] = *(const short8*)(BlB + (((wn * 4 + sn) * 64 + lane) * 16));
#pragma unroll
        for (int sm = 0; sm < 4; sm++)
#pragma unroll
            for (int sn = 0; sn < 4; sn++)
                acc[sm][sn] = __builtin_amdgcn_mfma_f32_16x16x32_bf16(
                    af[sm], bf[sn], acc[sm][sn], 0, 0, 0);
        __syncthreads();
    }

    // epilogue: C/D layout col=lane&15 (N), row=quad*4+reg (M).
    // even row = X frame, odd row = Y frame; even col = Re, odd col = Im.
    if (tid < 64) msePart[tid] = 0.f;
    __syncthreads();
    const bool evenLane = (l15 & 1) == 0;
#pragma unroll
    for (int sm = 0; sm < 4; sm++) {
#pragma unroll
        for (int sn = 0; sn < 4; sn++) {
#pragma unroll
            for (int rp = 0; rp < 2; rp++) {
                float vE = acc[sm][sn][2 * rp];       // X (even row), this col
                float vO = acc[sm][sn][2 * rp + 1];   // Y (odd row), this col
                float pE = __shfl_xor(vE, 1, 64);     // partner col (Re<->Im)
                float pO = __shfl_xor(vO, 1, 64);
                if (evenLane) {
                    float magX = sqrtf(vE * vE + pE * pE);
                    float magY = sqrtf(vO * vO + pO * pO);
                    float d = magX - magY;
                    int fl = (wn * 64 + sn * 16 + l15) >> 1;
                    atomicAdd(&msePart[fl], d * d);
                }
            }
        }
    }
    __syncthreads();
    if (tid < 64) atomicAdd(&mse_sum[(tileN >> 1) + tid], msePart[tid]);
}

// ---------------- final: out = sum_f mse_sum[f]*invW[f] / (4105*22528*1024) ----------------
__global__ void final_kernel(const float* __restrict__ mse_sum,
                             const float* __restrict__ invW,
                             float* __restrict__ out) {
    __shared__ float red[4];
    const int tid = threadIdx.x;
    float lo = 0.f;
    for (int f = tid; f < 1024; f += 256) lo += mse_sum[f] * invW[f];
    lo = wave_reduce(lo);
    if ((tid & 63) == 0) red[tid >> 6] = lo;
    __syncthreads();
    if (tid == 0) {
        float tot = red[0] + red[1] + red[2] + red[3];
        out[0] = tot * (float)(1.0 / (4105.0 * 22528.0 * 1024.0));
    }
}

extern "C" void kernel_launch(void* const* d_in, const int* in_sizes, int n_in,
                              void* d_out, int out_size, void* d_ws, size_t ws_size,
                              hipStream_t stream) {
    const float* x = (const float*)d_in[0];
    const float* y = (const float*)d_in[1];
    float* out = (float*)d_out;

    float* wsf = (float*)d_ws;
    float* mse_sum = wsf;             // 1024 floats
    float* invW = wsf + 1024;         // 1024 floats
    float* ar = wsf + 2048;           // 2048*12 floats (ends at byte 106496)
    __hip_bfloat16* A = (__hip_bfloat16*)((char*)d_ws + 131072);     // 8320*2048*2 B (permuted)
    __hip_bfloat16* Bt = (__hip_bfloat16*)((char*)d_ws + 34209792);  // 2048*2048*2 B (permuted)

    prep_kernel<<<PREP_BLOCKS, 256, 0, stream>>>(x, y, A, Bt, ar, wsf);
    invw_kernel<<<dim3(4, 128), 256, 0, stream>>>(ar, invW);
    gemm_mse_kernel<<<dim3(NDIM / 128, MPAD / 128), 256, 0, stream>>>(A, Bt, mse_sum);
    final_kernel<<<1, 256, 0, stream>>>(mse_sum, invW, out);
}

// Round 6
// 165.729 us; speedup vs baseline: 1.8700x; 1.3853x over previous
//
#include <hip/hip_runtime.h>
#include <hip/hip_bf16.h>

#define PI_D 3.14159265358979323846
#define L_TOTAL 2097152
#define NFRAMES 4105      // 1 + L/511
#define NBLK    4108      // hop-blocks b: frames t use blocks t..t+3, t<=4104
#define MROWS_P 8216      // 2*NBLK (x/y interleaved)
#define MPAD    8320      // 65 * 128
#define KP      512       // 511 padded
#define NDIM    2048      // 1024 bins * (Re,Im)
#define PSTRIDE 8224      // Pt row stride (>= MROWS_P + 8 slack, 16B aligned)

// Permuted ("tile-fragment") global layout for Ap and Bp, 16B chunks of 8 bf16:
//   chunk16B(row, kc) = (row>>4)*1024 + kc*16 + (row&15),  kc = k/8 in [0,64)
// GEMM staging reads contiguous 1KB per wave AND LDS lands in MFMA fragment
// order (ds_read_b128 conflict-free; verified rounds 2-5).

#define FRAMES_BLOCKS 2080   // 8320*64/256
#define BASIS_BLOCKS  512    // 2048*64/256
#define BURG_BLOCKS   512
#define PREP_BLOCKS   (FRAMES_BLOCKS + BASIS_BLOCKS + BURG_BLOCKS)

typedef __attribute__((ext_vector_type(8))) short short8;
typedef __attribute__((ext_vector_type(4))) short short4v;
typedef __attribute__((ext_vector_type(4))) float floatx4;

typedef __attribute__((address_space(1))) void gvoid_as1;
typedef __attribute__((address_space(3))) void lvoid_as3;

__device__ __forceinline__ void gld_lds16(const void* g, void* l) {
    __builtin_amdgcn_global_load_lds((gvoid_as1*)g, (lvoid_as3*)l, 16, 0, 0);
}

__device__ __forceinline__ float b2f(short v) {
    unsigned int u = ((unsigned int)(unsigned short)v) << 16;
    return __uint_as_float(u);
}

__device__ __forceinline__ float xorall(float v) {
    v += __shfl_xor(v, 1, 64);
    v += __shfl_xor(v, 2, 64);
    v += __shfl_xor(v, 4, 64);
    v += __shfl_xor(v, 8, 64);
    v += __shfl_xor(v, 16, 64);
    v += __shfl_xor(v, 32, 64);
    return v;
}

__device__ __forceinline__ float wave_reduce(float v) {
    v += __shfl_down(v, 32, 64);
    v += __shfl_down(v, 16, 64);
    v += __shfl_down(v, 8, 64);
    v += __shfl_down(v, 4, 64);
    v += __shfl_down(v, 2, 64);
    v += __shfl_down(v, 1, 64);
    return v;
}

// ---------------- frames branch: build Ap (bf16, permuted chunk layout) ----------------
// Ap[row=2b+s][n] = xp_s[511b + n], n<511 (col 511 = 0). Store-coalesced (r4 pattern).
__device__ __forceinline__ void frames_body(int bid, int tid,
                                            const float* __restrict__ x,
                                            const float* __restrict__ y,
                                            __hip_bfloat16* __restrict__ A) {
    const int ci = bid * 256 + tid;          // chunk index
    const int rb = ci >> 10;
    const int kc = (ci >> 4) & 63;
    const int rowIn = ci & 15;
    const int row = rb * 16 + rowIn;
    __hip_bfloat16 tmp[8];
    if (row < MROWS_P) {
        const int b = row >> 1;
        const float* src = (row & 1) ? y : x;
        const int base = b * 511 + kc * 8 - 1023;   // xp index - 1023
#pragma unroll
        for (int e = 0; e < 8; e++) {
            const int n = kc * 8 + e;
            float v = 0.f;
            if (n < 511) {
                int p = base + e;
                if (p < 0) p = -p;
                else if (p >= L_TOTAL) p = 2 * L_TOTAL - 2 - p;
                v = src[p];
            }
            tmp[e] = __float2bfloat16(v);
        }
    } else {
#pragma unroll
        for (int e = 0; e < 8; e++) tmp[e] = __float2bfloat16(0.f);
    }
    *(short8*)((char*)A + (size_t)ci * 16) = *(short8*)tmp;
}

// ---------------- basis branch: Bp (bf16, permuted chunk layout) ----------------
// Bp[row=2f+c][n] = cos(2pi f n/2046) (c=0) / -sin (c=1), n<511.
__device__ __forceinline__ void basis_body(int bid, int tid,
                                           __hip_bfloat16* __restrict__ Bt) {
    const int ci = bid * 256 + tid;
    const int rb = ci >> 10;
    const int kc = (ci >> 4) & 63;
    const int rowIn = ci & 15;
    const int row = rb * 16 + rowIn;
    const int f = row >> 1;
    const bool isSin = row & 1;
    __hip_bfloat16 tmp[8];
#pragma unroll
    for (int e = 0; e < 8; e++) {
        const int n = kc * 8 + e;
        float v = 0.f;
        if (n < 511) {
            const int m = (f * n) % 2046;            // exact angle mod 2pi
            const float ang = (float)m * (float)(PI_D / 1023.0);
            float s, c;
            __sincosf(ang, &s, &c);
            v = isSin ? -s : c;
        }
        tmp[e] = __float2bfloat16(v);
    }
    *(short8*)((char*)Bt + (size_t)ci * 16) = *(short8*)tmp;
}

// ---------------- burg branch: one WAVE per 1024-sample audio block ----------------
__device__ __forceinline__ void burg_body(int bid, int tid,
                                          const float* __restrict__ y,
                                          float* __restrict__ ar_out,
                                          float* __restrict__ wsf) {
    if (bid < 8) wsf[bid * 256 + tid] = 0.f;

    const int lane = tid & 63;
    const int wid = tid >> 6;
    const int blk = bid * 4 + wid;
    const float4* yb4 = (const float4*)(y + (size_t)blk * 1024) + lane * 4;

    float t[16];
#pragma unroll
    for (int q = 0; q < 4; q++) {
        float4 v = yb4[q];
        t[q * 4 + 0] = v.x; t[q * 4 + 1] = v.y;
        t[q * 4 + 2] = v.z; t[q * 4 + 3] = v.w;
    }
    float b[16], f[16];
#pragma unroll
    for (int r = 0; r < 16; r++) b[r] = t[r];
#pragma unroll
    for (int r = 0; r < 15; r++) f[r] = t[r + 1];
    {
        float nb = __shfl_down(t[0], 1, 64);
        f[15] = (lane == 63) ? 0.f : nb;
        if (lane == 63) b[15] = 0.f;
    }

    float den = 0.f;
#pragma unroll
    for (int r = 0; r < 16; r++) den += f[r] * f[r] + b[r] * b[r];
    den = xorall(den);

    float ar_s[13];
    ar_s[0] = 1.f;
#pragma unroll
    for (int j = 1; j < 13; j++) ar_s[j] = 0.f;

#pragma unroll
    for (int i = 0; i < 12; i++) {
        float num = 0.f;
#pragma unroll
        for (int r = 0; r < 16; r++) num += f[r] * b[r];
        num = xorall(num);
        const float k = -2.f * num / den;

        float fu[16], bu[16];
#pragma unroll
        for (int r = 0; r < 16; r++) {
            fu[r] = f[r] + k * b[r];
            bu[r] = b[r] + k * f[r];
        }
        const float f0 = __shfl(fu[0], 0, 64);
        const int pos = 1022 - i;
        const int L = pos >> 4, S = pos & 15;
        const float blast = __shfl(bu[S], L, 64);

        den = (1.f - k * k) * den - blast * blast - f0 * f0;

        float nf = __shfl_down(fu[0], 1, 64);
#pragma unroll
        for (int r = 0; r < 15; r++) f[r] = fu[r + 1];
        f[15] = (lane == 63) ? 0.f : nf;
#pragma unroll
        for (int r = 0; r < 16; r++) b[r] = bu[r];
        if (lane == L) b[S] = 0.f;

        float tmp[13];
#pragma unroll
        for (int js = 1; js <= i + 1; js++) tmp[js] = ar_s[js] + k * ar_s[i + 1 - js];
#pragma unroll
        for (int js = 1; js <= i + 1; js++) ar_s[js] = tmp[js];
    }

#pragma unroll
    for (int j = 0; j < 12; j++)
        if (lane == j) ar_out[(size_t)blk * 12 + j] = ar_s[j];
}

// ---------------- fused prep: frames | basis | burg (independent) ----------------
__global__ __launch_bounds__(256) void prep_kernel(const float* __restrict__ x,
                                                   const float* __restrict__ y,
                                                   __hip_bfloat16* __restrict__ A,
                                                   __hip_bfloat16* __restrict__ Bt,
                                                   float* __restrict__ ar,
                                                   float* __restrict__ wsf) {
    const int bid = blockIdx.x;
    const int tid = threadIdx.x;
    if (bid < FRAMES_BLOCKS) {
        frames_body(bid, tid, x, y, A);
    } else if (bid < FRAMES_BLOCKS + BASIS_BLOCKS) {
        basis_body(bid - FRAMES_BLOCKS, tid, Bt);
    } else {
        burg_body(bid - FRAMES_BLOCKS - BASIS_BLOCKS, tid, y, ar, wsf);
    }
}

// ---------------- invW[f] = sum_{b,kk} |den(b,kk,f)| / |num(b,kk,f)| ----------------
__global__ __launch_bounds__(256) void invw_kernel(const float* __restrict__ ar,
                                                   float* __restrict__ invW) {
    __shared__ float sar[16][12];
    const int tid = threadIdx.x;
    const int f = blockIdx.x * 256 + tid;
    const int b0 = blockIdx.y * 16;
    if (tid < 16 * 12) ((float*)sar)[tid] = ar[(size_t)b0 * 12 + tid];
    __syncthreads();

    const float omega = (float)(PI_D / 1024.0) * (float)f;
    float sw, cw;
    __sincosf(omega, &sw, &cw);

    float acc = 0.f;
#pragma unroll 4
    for (int bb = 0; bb < 16; bb++) {
        float a0 = sar[bb][0];
        float nr = a0, ni = 0.f, dr = a0, di = 0.f;
        float er = 1.f, ei = 0.f;
        float g1p = 1.f, g2p = 1.f;
#pragma unroll
        for (int j = 1; j < 12; j++) {
            float er2 = er * cw + ei * sw;
            float ei2 = ei * cw - er * sw;
            er = er2; ei = ei2;
            g1p *= 0.92f; g2p *= 0.6f;
            float aj = sar[bb][j];
            float a1 = aj * g1p, a2 = aj * g2p;
            nr += a2 * er; ni += a2 * ei;
            dr += a1 * er; di += a1 * ei;
            float D = dr * dr + di * di;
            float Nn = nr * nr + ni * ni;
            acc += D * __builtin_amdgcn_rsqf(D * Nn);
        }
    }
    atomicAdd(&invW[f], acc);
}

// ---------------- P-GEMM: Pt[n][m] = sum_k Ap[m][k]*Bp[n][k], K=512 ----------------
// 128x128 tile, 4 waves of 4x4 16x16x32 MFMA, BK=32 (16 iters). Output bf16,
// N-major (Pt stride PSTRIDE in m) for the combine kernel's contiguous reads.
__global__ __launch_bounds__(256) void gemm_p_kernel(
    const __hip_bfloat16* __restrict__ A, const __hip_bfloat16* __restrict__ Bt,
    __hip_bfloat16* __restrict__ Pt) {
    __shared__ __align__(16) __hip_bfloat16 Al[128 * 32];
    __shared__ __align__(16) __hip_bfloat16 Bl[128 * 32];

    const int tid = threadIdx.x;
    const int lane = tid & 63;
    const int w = tid >> 6;
    const int wm = w >> 1, wn = w & 1;
    const int q = lane >> 4, l15 = lane & 15;
    const int tileN = blockIdx.x * 128;
    const int tileM = blockIdx.y * 128;

    floatx4 acc[4][4];
#pragma unroll
    for (int i = 0; i < 4; i++)
#pragma unroll
        for (int j = 0; j < 4; j++) acc[i][j] = (floatx4){0.f, 0.f, 0.f, 0.f};

    // staging: row-block = 16 rows x 64 kc = 1024 chunks = 16KB
    const int rl = tid & 15;
    const int qq = (tid >> 4) & 3;
    const int gg0 = tid >> 6;
    const char* pA0 = (const char*)A + ((((size_t)(tileM >> 4) + gg0) << 10) + qq * 16 + rl) * 16;
    const char* pA1 = pA0 + (size_t)4 * 16384;
    const char* pB0 = (const char*)Bt + ((((size_t)(tileN >> 4) + gg0) << 10) + qq * 16 + rl) * 16;
    const char* pB1 = pB0 + (size_t)4 * 16384;
    char* AlB = (char*)Al;
    char* BlB = (char*)Bl;

    for (int it = 0; it < KP / 32; it++) {
        gld_lds16(pA0, AlB + tid * 16);
        gld_lds16(pA1, AlB + (tid + 256) * 16);
        gld_lds16(pB0, BlB + tid * 16);
        gld_lds16(pB1, BlB + (tid + 256) * 16);
        pA0 += 1024; pA1 += 1024; pB0 += 1024; pB1 += 1024;
        __syncthreads();

        short8 af[4], bf[4];
#pragma unroll
        for (int sm = 0; sm < 4; sm++)
            af[sm] = *(const short8*)(AlB + (((wm * 4 + sm) * 64 + lane) * 16));
#pragma unroll
        for (int sn = 0; sn < 4; sn++)
            bf[sn] = *(const short8*)(BlB + (((wn * 4 + sn) * 64 + lane) * 16));
#pragma unroll
        for (int sm = 0; sm < 4; sm++)
#pragma unroll
            for (int sn = 0; sn < 4; sn++)
                acc[sm][sn] = __builtin_amdgcn_mfma_f32_16x16x32_bf16(
                    af[sm], bf[sn], acc[sm][sn], 0, 0, 0);
        __syncthreads();
    }

    // epilogue: C/D col=lane&15 (N), row=quad*4+reg (M). Write Pt[n][m] bf16,
    // 4 consecutive m per lane -> 8B store.
#pragma unroll
    for (int sm = 0; sm < 4; sm++) {
        const int rowBase = tileM + wm * 64 + sm * 16 + q * 4;
        if (rowBase >= MROWS_P) continue;      // pad rows
#pragma unroll
        for (int sn = 0; sn < 4; sn++) {
            const int colG = tileN + wn * 64 + sn * 16 + l15;
            short4v pk;
#pragma unroll
            for (int r = 0; r < 4; r++) {
                __hip_bfloat16 h = __float2bfloat16(acc[sm][sn][r]);
                pk[r] = *(short*)&h;
            }
            *(short4v*)((char*)Pt + ((size_t)colG * PSTRIDE + rowBase) * 2) = pk;
        }
    }
}

// ---------------- combine: X_t[f] = sum_h W_h[f] P_{t+h}[f] + tail; mse reduce ----
// wave owns one f; lane handles 4 frames via two aligned 16B loads per Re/Im row.
__global__ __launch_bounds__(256) void combine_kernel(
    const __hip_bfloat16* __restrict__ Pt,
    const float* __restrict__ x, const float* __restrict__ y,
    float* __restrict__ mse_sum) {
    const int tid = threadIdx.x;
    const int lane = tid & 63;
    const int wid = tid >> 6;
    const int f = blockIdx.x * 4 + wid;      // 0..1023
    const int ty = blockIdx.y;               // 0..16

    // twiddles: W_h = e^{-2pi i f*511h/2046}; tails at offsets 2044, 2045
    float wc[4], ws[4];
    wc[0] = 1.f; ws[0] = 0.f;
#pragma unroll
    for (int h = 1; h < 4; h++) {
        int m = (511 * h * f) % 2046;
        float s, c;
        __sincosf((float)m * (float)(PI_D / 1023.0), &s, &c);
        wc[h] = c; ws[h] = -s;
    }
    float wtc0, wts0, wtc1, wts1;
    {
        int m = (2044 * f) % 2046;
        float s, c;
        __sincosf((float)m * (float)(PI_D / 1023.0), &s, &c);
        wtc0 = c; wts0 = -s;
        m = (2045 * f) % 2046;
        __sincosf((float)m * (float)(PI_D / 1023.0), &s, &c);
        wtc1 = c; wts1 = -s;
    }

    const __hip_bfloat16* rowRe = Pt + (size_t)(2 * f) * PSTRIDE;
    const __hip_bfloat16* rowIm = rowRe + PSTRIDE;

    float acc = 0.f;
    const int tt0 = ty * 256 + 4 * lane;
    if (tt0 < NFRAMES) {
        // cols [2tt0, 2tt0+16): P_{t0..t0+3+} for s=0,1 interleaved (col=2b+s)
        short8 re0 = *(const short8*)(rowRe + 2 * tt0);
        short8 re1 = *(const short8*)(rowRe + 2 * tt0 + 8);
        short8 im0 = *(const short8*)(rowIm + 2 * tt0);
        short8 im1 = *(const short8*)(rowIm + 2 * tt0 + 8);
        float vr[16], vi[16];
#pragma unroll
        for (int j = 0; j < 8; j++) {
            vr[j] = b2f(re0[j]); vr[j + 8] = b2f(re1[j]);
            vi[j] = b2f(im0[j]); vi[j + 8] = b2f(im1[j]);
        }
#pragma unroll
        for (int d = 0; d < 4; d++) {
            const int tt = tt0 + d;
            if (tt >= NFRAMES) break;
            float xr = 0.f, xi = 0.f, yr = 0.f, yi = 0.f;
#pragma unroll
            for (int h = 0; h < 4; h++) {
                const int qx = 2 * d + 2 * h;
                xr += wc[h] * vr[qx] - ws[h] * vi[qx];
                xi += wc[h] * vi[qx] + ws[h] * vr[qx];
                const int qy = qx + 1;
                yr += wc[h] * vr[qy] - ws[h] * vi[qy];
                yi += wc[h] * vi[qy] + ws[h] * vr[qy];
            }
            // tail samples at frame positions 2044, 2045
            int p0 = tt * 511 + 1021;
            int m0 = (p0 >= L_TOTAL) ? 2 * L_TOTAL - 2 - p0 : p0;
            int p1 = p0 + 1;
            int m1 = (p1 >= L_TOTAL) ? 2 * L_TOTAL - 2 - p1 : p1;
            float sx0 = x[m0], sx1 = x[m1];
            float sy0 = y[m0], sy1 = y[m1];
            xr += wtc0 * sx0 + wtc1 * sx1;
            xi += wts0 * sx0 + wts1 * sx1;
            yr += wtc0 * sy0 + wtc1 * sy1;
            yi += wts0 * sy0 + wts1 * sy1;
            float dm = sqrtf(xr * xr + xi * xi) - sqrtf(yr * yr + yi * yi);
            acc += dm * dm;
        }
    }
    acc = xorall(acc);
    if (lane == 0) atomicAdd(&mse_sum[f], acc);
}

// ---------------- final: out = sum_f mse_sum[f]*invW[f] / (4105*22528*1024) ----------------
__global__ void final_kernel(const float* __restrict__ mse_sum,
                             const float* __restrict__ invW,
                             float* __restrict__ out) {
    __shared__ float red[4];
    const int tid = threadIdx.x;
    float lo = 0.f;
    for (int f = tid; f < 1024; f += 256) lo += mse_sum[f] * invW[f];
    lo = wave_reduce(lo);
    if ((tid & 63) == 0) red[tid >> 6] = lo;
    __syncthreads();
    if (tid == 0) {
        float tot = red[0] + red[1] + red[2] + red[3];
        out[0] = tot * (float)(1.0 / (4105.0 * 22528.0 * 1024.0));
    }
}

extern "C" void kernel_launch(void* const* d_in, const int* in_sizes, int n_in,
                              void* d_out, int out_size, void* d_ws, size_t ws_size,
                              hipStream_t stream) {
    const float* x = (const float*)d_in[0];
    const float* y = (const float*)d_in[1];
    float* out = (float*)d_out;

    float* wsf = (float*)d_ws;
    float* mse_sum = wsf;             // 1024 floats
    float* invW = wsf + 1024;         // 1024 floats
    float* ar = wsf + 2048;           // 2048*12 floats (ends at byte 106496)
    __hip_bfloat16* Ap = (__hip_bfloat16*)((char*)d_ws + 131072);    // 8320*512*2 = 8,519,680 B
    __hip_bfloat16* Bp = (__hip_bfloat16*)((char*)d_ws + 8650752);   // 2048*512*2 = 2,097,152 B
    __hip_bfloat16* Pt = (__hip_bfloat16*)((char*)d_ws + 10747904);  // 2048*8224*2 = 33,685,504 B

    prep_kernel<<<PREP_BLOCKS, 256, 0, stream>>>(x, y, Ap, Bp, ar, wsf);
    invw_kernel<<<dim3(4, 128), 256, 0, stream>>>(ar, invW);
    gemm_p_kernel<<<dim3(NDIM / 128, MPAD / 128), 256, 0, stream>>>(Ap, Bp, Pt);
    combine_kernel<<<dim3(256, 17), 256, 0, stream>>>(Pt, x, y, mse_sum);
    final_kernel<<<1, 256, 0, stream>>>(mse_sum, invW, out);
}

// Round 7
// 145.134 us; speedup vs baseline: 2.1354x; 1.1419x over previous
//
#include <hip/hip_runtime.h>
#include <hip/hip_bf16.h>

#define PI_D 3.14159265358979323846
#define L_TOTAL 2097152
#define NFRAMES 4105      // 1 + L/511
#define NBLK    4108      // hop-blocks b: frames t use blocks t..t+3 + 2 samples of t+4
#define MROWS_P 8216      // 2*NBLK (x/y interleaved)
#define MPAD    8320      // 65 * 128
#define KP      512       // 511 padded
#define NDIM    2048      // 1024 bins * (Re,Im)
#define PSTRIDE 8224      // Pt row stride (>= MROWS_P + 8 slack, 16B aligned)

// Permuted ("tile-fragment") global layout for Ap and Bp, 16B chunks of 8 bf16:
//   chunk16B(row, kc) = (row>>4)*1024 + kc*16 + (row&15),  kc = k/8 in [0,64)
// GEMM staging reads contiguous 1KB per wave AND LDS lands in MFMA fragment
// order (ds_read_b128 conflict-free; verified rounds 2-6).

#define FRAMES_BLOCKS 2080   // 8320*64/256
#define BASIS_BLOCKS  512    // 2048*64/256
#define SARR_BLOCKS   17     // 4352 S entries
#define BURG_BLOCKS   512
#define PREP_BLOCKS   (FRAMES_BLOCKS + BASIS_BLOCKS + SARR_BLOCKS + BURG_BLOCKS)

typedef __attribute__((ext_vector_type(8))) short short8;
typedef __attribute__((ext_vector_type(4))) short short4v;
typedef __attribute__((ext_vector_type(4))) float floatx4;

typedef __attribute__((address_space(1))) void gvoid_as1;
typedef __attribute__((address_space(3))) void lvoid_as3;

__device__ __forceinline__ void gld_lds16(const void* g, void* l) {
    __builtin_amdgcn_global_load_lds((gvoid_as1*)g, (lvoid_as3*)l, 16, 0, 0);
}

__device__ __forceinline__ float b2f(short v) {
    unsigned int u = ((unsigned int)(unsigned short)v) << 16;
    return __uint_as_float(u);
}

__device__ __forceinline__ float xorall(float v) {
    v += __shfl_xor(v, 1, 64);
    v += __shfl_xor(v, 2, 64);
    v += __shfl_xor(v, 4, 64);
    v += __shfl_xor(v, 8, 64);
    v += __shfl_xor(v, 16, 64);
    v += __shfl_xor(v, 32, 64);
    return v;
}

__device__ __forceinline__ float wave_reduce(float v) {
    v += __shfl_down(v, 32, 64);
    v += __shfl_down(v, 16, 64);
    v += __shfl_down(v, 8, 64);
    v += __shfl_down(v, 4, 64);
    v += __shfl_down(v, 2, 64);
    v += __shfl_down(v, 1, 64);
    return v;
}

// ---------------- frames branch: build Ap (bf16, permuted chunk layout) ----------------
// Ap[row=2b+s][n] = xp_s[511b + n], n<511 (col 511 = 0).
__device__ __forceinline__ void frames_body(int bid, int tid,
                                            const float* __restrict__ x,
                                            const float* __restrict__ y,
                                            __hip_bfloat16* __restrict__ A) {
    const int ci = bid * 256 + tid;          // chunk index
    const int rb = ci >> 10;
    const int kc = (ci >> 4) & 63;
    const int rowIn = ci & 15;
    const int row = rb * 16 + rowIn;
    __hip_bfloat16 tmp[8];
    if (row < MROWS_P) {
        const int b = row >> 1;
        const float* src = (row & 1) ? y : x;
        const int base = b * 511 + kc * 8 - 1023;   // xp index - 1023
#pragma unroll
        for (int e = 0; e < 8; e++) {
            const int n = kc * 8 + e;
            float v = 0.f;
            if (n < 511) {
                int p = base + e;
                if (p < 0) p = -p;
                else if (p >= L_TOTAL) p = 2 * L_TOTAL - 2 - p;
                v = src[p];
            }
            tmp[e] = __float2bfloat16(v);
        }
    } else {
#pragma unroll
        for (int e = 0; e < 8; e++) tmp[e] = __float2bfloat16(0.f);
    }
    *(short8*)((char*)A + (size_t)ci * 16) = *(short8*)tmp;
}

// ---------------- basis branch: Bp (bf16, permuted chunk layout) ----------------
__device__ __forceinline__ void basis_body(int bid, int tid,
                                           __hip_bfloat16* __restrict__ Bt) {
    const int ci = bid * 256 + tid;
    const int rb = ci >> 10;
    const int kc = (ci >> 4) & 63;
    const int rowIn = ci & 15;
    const int row = rb * 16 + rowIn;
    const int f = row >> 1;
    const bool isSin = row & 1;
    __hip_bfloat16 tmp[8];
#pragma unroll
    for (int e = 0; e < 8; e++) {
        const int n = kc * 8 + e;
        float v = 0.f;
        if (n < 511) {
            const int m = (f * n) % 2046;            // exact angle mod 2pi
            const float ang = (float)m * (float)(PI_D / 1023.0);
            float s, c;
            __sincosf(ang, &s, &c);
            v = isSin ? -s : c;
        }
        tmp[e] = __float2bfloat16(v);
    }
    *(short8*)((char*)Bt + (size_t)ci * 16) = *(short8*)tmp;
}

// ---------------- S branch: tail-sample table S[b] = (x0,x1,y0,y1) ----------------
// samples xp[511b], xp[511b+1] of both signals (reflect-padded).
__device__ __forceinline__ void sarr_body(int bid, int tid,
                                          const float* __restrict__ x,
                                          const float* __restrict__ y,
                                          float4* __restrict__ S) {
    const int b = bid * 256 + tid;          // 0..4351
    int p0 = 511 * b - 1023;
    int p1 = p0 + 1;
    int m0 = (p0 < 0) ? -p0 : ((p0 >= L_TOTAL) ? 2 * L_TOTAL - 2 - p0 : p0);
    int m1 = (p1 < 0) ? -p1 : ((p1 >= L_TOTAL) ? 2 * L_TOTAL - 2 - p1 : p1);
    S[b] = make_float4(x[m0], x[m1], y[m0], y[m1]);
}

// ---------------- burg branch: one WAVE per 1024-sample audio block ----------------
__device__ __forceinline__ void burg_body(int bid, int tid,
                                          const float* __restrict__ y,
                                          float* __restrict__ ar_out,
                                          float* __restrict__ wsf) {
    if (bid < 8) wsf[bid * 256 + tid] = 0.f;

    const int lane = tid & 63;
    const int wid = tid >> 6;
    const int blk = bid * 4 + wid;
    const float4* yb4 = (const float4*)(y + (size_t)blk * 1024) + lane * 4;

    float t[16];
#pragma unroll
    for (int q = 0; q < 4; q++) {
        float4 v = yb4[q];
        t[q * 4 + 0] = v.x; t[q * 4 + 1] = v.y;
        t[q * 4 + 2] = v.z; t[q * 4 + 3] = v.w;
    }
    float b[16], f[16];
#pragma unroll
    for (int r = 0; r < 16; r++) b[r] = t[r];
#pragma unroll
    for (int r = 0; r < 15; r++) f[r] = t[r + 1];
    {
        float nb = __shfl_down(t[0], 1, 64);
        f[15] = (lane == 63) ? 0.f : nb;
        if (lane == 63) b[15] = 0.f;
    }

    float den = 0.f;
#pragma unroll
    for (int r = 0; r < 16; r++) den += f[r] * f[r] + b[r] * b[r];
    den = xorall(den);

    float ar_s[13];
    ar_s[0] = 1.f;
#pragma unroll
    for (int j = 1; j < 13; j++) ar_s[j] = 0.f;

#pragma unroll
    for (int i = 0; i < 12; i++) {
        float num = 0.f;
#pragma unroll
        for (int r = 0; r < 16; r++) num += f[r] * b[r];
        num = xorall(num);
        const float k = -2.f * num / den;

        float fu[16], bu[16];
#pragma unroll
        for (int r = 0; r < 16; r++) {
            fu[r] = f[r] + k * b[r];
            bu[r] = b[r] + k * f[r];
        }
        const float f0 = __shfl(fu[0], 0, 64);
        const int pos = 1022 - i;
        const int L = pos >> 4, S = pos & 15;
        const float blast = __shfl(bu[S], L, 64);

        den = (1.f - k * k) * den - blast * blast - f0 * f0;

        float nf = __shfl_down(fu[0], 1, 64);
#pragma unroll
        for (int r = 0; r < 15; r++) f[r] = fu[r + 1];
        f[15] = (lane == 63) ? 0.f : nf;
#pragma unroll
        for (int r = 0; r < 16; r++) b[r] = bu[r];
        if (lane == L) b[S] = 0.f;

        float tmp[13];
#pragma unroll
        for (int js = 1; js <= i + 1; js++) tmp[js] = ar_s[js] + k * ar_s[i + 1 - js];
#pragma unroll
        for (int js = 1; js <= i + 1; js++) ar_s[js] = tmp[js];
    }

#pragma unroll
    for (int j = 0; j < 12; j++)
        if (lane == j) ar_out[(size_t)blk * 12 + j] = ar_s[j];
}

// ---------------- fused prep: frames | basis | S | burg (independent) ----------------
__global__ __launch_bounds__(256) void prep_kernel(const float* __restrict__ x,
                                                   const float* __restrict__ y,
                                                   __hip_bfloat16* __restrict__ A,
                                                   __hip_bfloat16* __restrict__ Bt,
                                                   float4* __restrict__ S,
                                                   float* __restrict__ ar,
                                                   float* __restrict__ wsf) {
    const int bid = blockIdx.x;
    const int tid = threadIdx.x;
    if (bid < FRAMES_BLOCKS) {
        frames_body(bid, tid, x, y, A);
    } else if (bid < FRAMES_BLOCKS + BASIS_BLOCKS) {
        basis_body(bid - FRAMES_BLOCKS, tid, Bt);
    } else if (bid < FRAMES_BLOCKS + BASIS_BLOCKS + SARR_BLOCKS) {
        sarr_body(bid - FRAMES_BLOCKS - BASIS_BLOCKS, tid, x, y, S);
    } else {
        burg_body(bid - FRAMES_BLOCKS - BASIS_BLOCKS - SARR_BLOCKS, tid, y, ar, wsf);
    }
}

// ---------------- invW[f] = sum_{b,kk} |den(b,kk,f)| / |num(b,kk,f)| ----------------
__global__ __launch_bounds__(256) void invw_kernel(const float* __restrict__ ar,
                                                   float* __restrict__ invW) {
    __shared__ float sar[16][12];
    const int tid = threadIdx.x;
    const int f = blockIdx.x * 256 + tid;
    const int b0 = blockIdx.y * 16;
    if (tid < 16 * 12) ((float*)sar)[tid] = ar[(size_t)b0 * 12 + tid];
    __syncthreads();

    const float omega = (float)(PI_D / 1024.0) * (float)f;
    float sw, cw;
    __sincosf(omega, &sw, &cw);

    float acc = 0.f;
#pragma unroll 4
    for (int bb = 0; bb < 16; bb++) {
        float a0 = sar[bb][0];
        float nr = a0, ni = 0.f, dr = a0, di = 0.f;
        float er = 1.f, ei = 0.f;
        float g1p = 1.f, g2p = 1.f;
#pragma unroll
        for (int j = 1; j < 12; j++) {
            float er2 = er * cw + ei * sw;
            float ei2 = ei * cw - er * sw;
            er = er2; ei = ei2;
            g1p *= 0.92f; g2p *= 0.6f;
            float aj = sar[bb][j];
            float a1 = aj * g1p, a2 = aj * g2p;
            nr += a2 * er; ni += a2 * ei;
            dr += a1 * er; di += a1 * ei;
            float D = dr * dr + di * di;
            float Nn = nr * nr + ni * ni;
            acc += D * __builtin_amdgcn_rsqf(D * Nn);
        }
    }
    atomicAdd(&invW[f], acc);
}

// ---------------- P-GEMM: Pt[n][m] = sum_k Ap[m][k]*Bp[n][k], K=512 ----------------
__global__ __launch_bounds__(256) void gemm_p_kernel(
    const __hip_bfloat16* __restrict__ A, const __hip_bfloat16* __restrict__ Bt,
    __hip_bfloat16* __restrict__ Pt) {
    __shared__ __align__(16) __hip_bfloat16 Al[128 * 32];
    __shared__ __align__(16) __hip_bfloat16 Bl[128 * 32];

    const int tid = threadIdx.x;
    const int lane = tid & 63;
    const int w = tid >> 6;
    const int wm = w >> 1, wn = w & 1;
    const int q = lane >> 4, l15 = lane & 15;
    const int tileN = blockIdx.x * 128;
    const int tileM = blockIdx.y * 128;

    floatx4 acc[4][4];
#pragma unroll
    for (int i = 0; i < 4; i++)
#pragma unroll
        for (int j = 0; j < 4; j++) acc[i][j] = (floatx4){0.f, 0.f, 0.f, 0.f};

    const int rl = tid & 15;
    const int qq = (tid >> 4) & 3;
    const int gg0 = tid >> 6;
    const char* pA0 = (const char*)A + ((((size_t)(tileM >> 4) + gg0) << 10) + qq * 16 + rl) * 16;
    const char* pA1 = pA0 + (size_t)4 * 16384;
    const char* pB0 = (const char*)Bt + ((((size_t)(tileN >> 4) + gg0) << 10) + qq * 16 + rl) * 16;
    const char* pB1 = pB0 + (size_t)4 * 16384;
    char* AlB = (char*)Al;
    char* BlB = (char*)Bl;

    for (int it = 0; it < KP / 32; it++) {
        gld_lds16(pA0, AlB + tid * 16);
        gld_lds16(pA1, AlB + (tid + 256) * 16);
        gld_lds16(pB0, BlB + tid * 16);
        gld_lds16(pB1, BlB + (tid + 256) * 16);
        pA0 += 1024; pA1 += 1024; pB0 += 1024; pB1 += 1024;
        __syncthreads();

        short8 af[4], bf[4];
#pragma unroll
        for (int sm = 0; sm < 4; sm++)
            af[sm] = *(const short8*)(AlB + (((wm * 4 + sm) * 64 + lane) * 16));
#pragma unroll
        for (int sn = 0; sn < 4; sn++)
            bf[sn] = *(const short8*)(BlB + (((wn * 4 + sn) * 64 + lane) * 16));
#pragma unroll
        for (int sm = 0; sm < 4; sm++)
#pragma unroll
            for (int sn = 0; sn < 4; sn++)
                acc[sm][sn] = __builtin_amdgcn_mfma_f32_16x16x32_bf16(
                    af[sm], bf[sn], acc[sm][sn], 0, 0, 0);
        __syncthreads();
    }

    // epilogue: C/D col=lane&15 (N), row=quad*4+reg (M). Write Pt[n][m] bf16.
#pragma unroll
    for (int sm = 0; sm < 4; sm++) {
        const int rowBase = tileM + wm * 64 + sm * 16 + q * 4;
        if (rowBase >= MROWS_P) continue;      // pad rows
#pragma unroll
        for (int sn = 0; sn < 4; sn++) {
            const int colG = tileN + wn * 64 + sn * 16 + l15;
            short4v pk;
#pragma unroll
            for (int r = 0; r < 4; r++) {
                __hip_bfloat16 h = __float2bfloat16(acc[sm][sn][r]);
                pk[r] = *(short*)&h;
            }
            *(short4v*)((char*)Pt + ((size_t)colG * PSTRIDE + rowBase) * 2) = pk;
        }
    }
}

// ---------------- combine: X_t[f] = sum_h W_h[f] P_{t+h}[f] + W_tail.S[t+4]; mse ----
__global__ __launch_bounds__(256) void combine_kernel(
    const __hip_bfloat16* __restrict__ Pt,
    const float4* __restrict__ S,
    float* __restrict__ mse_sum) {
    const int tid = threadIdx.x;
    const int lane = tid & 63;
    const int wid = tid >> 6;
    const int f = blockIdx.x * 4 + wid;      // 0..1023
    const int ty = blockIdx.y;               // 0..16

    // twiddles: W_h = e^{-2pi i f*511h/2046}; tails at offsets 2044, 2045
    float wc[4], ws[4];
    wc[0] = 1.f; ws[0] = 0.f;
#pragma unroll
    for (int h = 1; h < 4; h++) {
        int m = (511 * h * f) % 2046;
        float s, c;
        __sincosf((float)m * (float)(PI_D / 1023.0), &s, &c);
        wc[h] = c; ws[h] = -s;
    }
    float wtc0, wts0, wtc1, wts1;
    {
        int m = (2044 * f) % 2046;
        float s, c;
        __sincosf((float)m * (float)(PI_D / 1023.0), &s, &c);
        wtc0 = c; wts0 = -s;
        m = (2045 * f) % 2046;
        __sincosf((float)m * (float)(PI_D / 1023.0), &s, &c);
        wtc1 = c; wts1 = -s;
    }

    const __hip_bfloat16* rowRe = Pt + (size_t)(2 * f) * PSTRIDE;
    const __hip_bfloat16* rowIm = rowRe + PSTRIDE;

    float acc = 0.f;
    const int tt0 = ty * 256 + 4 * lane;
    if (tt0 < NFRAMES) {
        short8 re0 = *(const short8*)(rowRe + 2 * tt0);
        short8 re1 = *(const short8*)(rowRe + 2 * tt0 + 8);
        short8 im0 = *(const short8*)(rowIm + 2 * tt0);
        short8 im1 = *(const short8*)(rowIm + 2 * tt0 + 8);
        float4 sT[4];
#pragma unroll
        for (int d = 0; d < 4; d++) sT[d] = S[tt0 + 4 + d];   // contiguous across wave
        float vr[16], vi[16];
#pragma unroll
        for (int j = 0; j < 8; j++) {
            vr[j] = b2f(re0[j]); vr[j + 8] = b2f(re1[j]);
            vi[j] = b2f(im0[j]); vi[j + 8] = b2f(im1[j]);
        }
#pragma unroll
        for (int d = 0; d < 4; d++) {
            const int tt = tt0 + d;
            if (tt >= NFRAMES) break;
            float xr = 0.f, xi = 0.f, yr = 0.f, yi = 0.f;
#pragma unroll
            for (int h = 0; h < 4; h++) {
                const int qx = 2 * d + 2 * h;
                xr += wc[h] * vr[qx] - ws[h] * vi[qx];
                xi += wc[h] * vi[qx] + ws[h] * vr[qx];
                const int qy = qx + 1;
                yr += wc[h] * vr[qy] - ws[h] * vi[qy];
                yi += wc[h] * vi[qy] + ws[h] * vr[qy];
            }
            // tail: first two samples of block t+4 from the S table
            const float4 sd = sT[d];
            xr += wtc0 * sd.x + wtc1 * sd.y;
            xi += wts0 * sd.x + wts1 * sd.y;
            yr += wtc0 * sd.z + wtc1 * sd.w;
            yi += wts0 * sd.z + wts1 * sd.w;
            float dm = sqrtf(xr * xr + xi * xi) - sqrtf(yr * yr + yi * yi);
            acc += dm * dm;
        }
    }
    acc = xorall(acc);
    if (lane == 0) atomicAdd(&mse_sum[f], acc);
}

// ---------------- final: out = sum_f mse_sum[f]*invW[f] / (4105*22528*1024) ----------------
__global__ void final_kernel(const float* __restrict__ mse_sum,
                             const float* __restrict__ invW,
                             float* __restrict__ out) {
    __shared__ float red[4];
    const int tid = threadIdx.x;
    float lo = 0.f;
    for (int f = tid; f < 1024; f += 256) lo += mse_sum[f] * invW[f];
    lo = wave_reduce(lo);
    if ((tid & 63) == 0) red[tid >> 6] = lo;
    __syncthreads();
    if (tid == 0) {
        float tot = red[0] + red[1] + red[2] + red[3];
        out[0] = tot * (float)(1.0 / (4105.0 * 22528.0 * 1024.0));
    }
}

extern "C" void kernel_launch(void* const* d_in, const int* in_sizes, int n_in,
                              void* d_out, int out_size, void* d_ws, size_t ws_size,
                              hipStream_t stream) {
    const float* x = (const float*)d_in[0];
    const float* y = (const float*)d_in[1];
    float* out = (float*)d_out;

    float* wsf = (float*)d_ws;
    float* mse_sum = wsf;             // 1024 floats
    float* invW = wsf + 1024;         // 1024 floats
    float* ar = wsf + 2048;           // 2048*12 floats (ends at byte 106496)
    float4* S = (float4*)((char*)d_ws + 106496);                     // 4352*16 = 69,632 B
    __hip_bfloat16* Ap = (__hip_bfloat16*)((char*)d_ws + 196608);    // 8320*512*2 = 8,519,680 B
    __hip_bfloat16* Bp = (__hip_bfloat16*)((char*)d_ws + 8716288);   // 2048*512*2 = 2,097,152 B
    __hip_bfloat16* Pt = (__hip_bfloat16*)((char*)d_ws + 10813440);  // 2048*8224*2 = 33,685,504 B

    prep_kernel<<<PREP_BLOCKS, 256, 0, stream>>>(x, y, Ap, Bp, S, ar, wsf);
    invw_kernel<<<dim3(4, 128), 256, 0, stream>>>(ar, invW);
    gemm_p_kernel<<<dim3(NDIM / 128, MPAD / 128), 256, 0, stream>>>(Ap, Bp, Pt);
    combine_kernel<<<dim3(256, 17), 256, 0, stream>>>(Pt, S, mse_sum);
    final_kernel<<<1, 256, 0, stream>>>(mse_sum, invW, out);
}